// Round 1
// baseline (890.540 us; speedup 1.0000x reference)
//
#include <hip/hip_runtime.h>

#define NB 2048
#define CNT 32768.0f   // per-channel count = B*H*W = 2048*16

// workspace float offsets
#define OFF_Y1   0          // 2048*32*16
#define OFF_Y2   1048576    // 2048*64*16
#define OFF_Y3   3145728    // 2048*128*16
#define OFF_Y4   7340032    // 2048*128*16
#define OFF_ST   11534336   // 4 layers x 256 (sum[c] at +c, sumsq at +128+c)
#define OFF_SC   11535360   // 4 layers x 256 (s at +c, t at +128+c)
#define OFF_W2T  11536384   // 32*9*64
#define OFF_W3T  11554816   // 64*9*128
#define OFF_WPT  11628544   // 128*9*18
#define OFF_WDT  11649280   // 128*9*128

__global__ void k_transpose(const float* __restrict__ w, float* __restrict__ wt, int CO, int CI) {
  int i = blockIdx.x * 256 + threadIdx.x;
  int tot = CO * CI * 9;
  if (i >= tot) return;
  int co = i / (CI * 9), r = i % (CI * 9), ci = r / 9, k = r % 9;
  wt[(ci * 9 + k) * CO + co] = w[i];
}

__global__ void k_finalize(const float* __restrict__ st, const float* __restrict__ g,
                           const float* __restrict__ b, float* __restrict__ sc, int C) {
  int c = threadIdx.x;
  if (c >= C) return;
  float m = st[c] / CNT;
  float v = st[128 + c] / CNT - m * m;
  float s = g[c] * rsqrtf(fmaxf(v, 0.f) + 1e-5f);
  sc[c] = s;
  sc[128 + c] = b[c] - m * s;
}

// conv1: 3->32, input raw x
__global__ __launch_bounds__(256) void k_conv1(const float* __restrict__ x, const float* __restrict__ W1,
                                               float* __restrict__ y1, float* __restrict__ st) {
  __shared__ float xs[48];
  __shared__ float w1s[864];
  __shared__ float sst[64];
  int b = blockIdx.x, t = threadIdx.x;
  if (t < 48) xs[t] = x[b * 48 + t];
  for (int i = t; i < 864; i += 256) w1s[i] = W1[i];
  if (t < 64) sst[t] = 0.f;
  __syncthreads();
  for (int r = 0; r < 2; ++r) {
    int o = t + r * 256;            // 0..511
    int co = o >> 4, p = o & 15, h = p >> 2, w = p & 3;
    float acc = 0.f;
    for (int ci = 0; ci < 3; ++ci) {
#pragma unroll
      for (int kx = 0; kx < 3; ++kx) {
        int ih = h + kx - 1;
        if (ih < 0 || ih > 3) continue;
#pragma unroll
        for (int ky = 0; ky < 3; ++ky) {
          int iw = w + ky - 1;
          if (iw < 0 || iw > 3) continue;
          acc += w1s[co * 27 + ci * 9 + kx * 3 + ky] * xs[ci * 16 + ih * 4 + iw];
        }
      }
    }
    acc = fmaxf(acc, 0.f);
    y1[b * 512 + o] = acc;
    atomicAdd(&sst[co], acc);
    atomicAdd(&sst[32 + co], acc * acc);
  }
  __syncthreads();
  if (t < 64) atomicAdd(&st[(t < 32) ? t : (96 + t)], sst[t]);
}

// generic conv 3x3 pad1 over 4x4, CO outputs, CI inputs (both pow2-ish), NG cin-groups
template <int CO, int CI, int NG>
__global__ __launch_bounds__(256) void k_conv(const float* __restrict__ yin, const float* __restrict__ wt,
                                              const float* __restrict__ sc, float* __restrict__ yout,
                                              float* __restrict__ st) {
  __shared__ float xs[CI * 16];
  __shared__ float pacc[NG][CO * 16];
  __shared__ float sst[2 * CO];
  int b = blockIdx.x, t = threadIdx.x;
  for (int i = t; i < CI * 16; i += 256) {
    int c = i >> 4;
    xs[i] = yin[b * CI * 16 + i] * sc[c] + sc[128 + c];  // fold producer BN
  }
  for (int i = t; i < 2 * CO; i += 256) sst[i] = 0.f;
  __syncthreads();
  int co = t & (CO - 1), g = t / CO;
  constexpr int CPG = CI / NG;
  float acc[16];
#pragma unroll
  for (int p = 0; p < 16; ++p) acc[p] = 0.f;
  for (int ci = g * CPG; ci < (g + 1) * CPG; ++ci) {
    float xr[16];
#pragma unroll
    for (int p = 0; p < 16; ++p) xr[p] = xs[ci * 16 + p];
    const float* wrow = wt + (ci * 9) * CO + co;
#pragma unroll
    for (int kx = 0; kx < 3; ++kx) {
#pragma unroll
      for (int ky = 0; ky < 3; ++ky) {
        float wv = wrow[(kx * 3 + ky) * CO];
#pragma unroll
        for (int h = 0; h < 4; ++h) {
          int ih = h + kx - 1;
          if (ih < 0 || ih > 3) continue;
#pragma unroll
          for (int w = 0; w < 4; ++w) {
            int iw = w + ky - 1;
            if (iw < 0 || iw > 3) continue;
            acc[h * 4 + w] += wv * xr[ih * 4 + iw];
          }
        }
      }
    }
  }
#pragma unroll
  for (int p = 0; p < 16; ++p) pacc[g][co * 16 + p] = acc[p];
  __syncthreads();
  for (int i = t; i < CO * 16; i += 256) {
    float v = 0.f;
#pragma unroll
    for (int g2 = 0; g2 < NG; ++g2) v += pacc[g2][i];
    v = fmaxf(v, 0.f);
    yout[b * CO * 16 + i] = v;
    int c = i >> 4;
    atomicAdd(&sst[c], v);
    atomicAdd(&sst[CO + c], v * v);
  }
  __syncthreads();
  for (int i = t; i < 2 * CO; i += 256)
    atomicAdd(&st[(i < CO) ? i : (128 - CO + i)], sst[i]);
}

// deformable conv: offsets (128->18 conv) + bilinear sampling + 128x1152 matvec (Wd), relu + stats
__global__ __launch_bounds__(256) void k_deform(const float* __restrict__ y3, const float* __restrict__ Wpt,
                                                const float* __restrict__ bp, const float* __restrict__ Wdt,
                                                const float* __restrict__ sc3, float* __restrict__ y4,
                                                float* __restrict__ st) {
  __shared__ float xn[128 * 16];    // normalized input image
  __shared__ float offs[18 * 16];   // offset conv output [ch][px]
  __shared__ int qidx[16 * 9 * 4];  // sampling: interior index or -1
  __shared__ float qwgt[16 * 9 * 4];
  __shared__ float xoff[64 * 9 * 16];  // bilinear-sampled tile, one 64-cin chunk [cl][n][px]
  __shared__ float sst[256];
  int b = blockIdx.x, t = threadIdx.x;
  // A: load + normalize
  for (int i = t; i < 2048; i += 256) {
    int c = i >> 4;
    xn[i] = y3[b * 2048 + i] * sc3[c] + sc3[128 + c];
  }
  sst[t] = 0.f;
  if (t + 0 < 256) {}  // (256 threads cover sst exactly)
  __syncthreads();
  // B: offset conv partials: o = t&31 (active o<18), g = t>>5 covers 16 cin each
  {
    int o = t & 31, g = t >> 5;
    float acc[16];
#pragma unroll
    for (int p = 0; p < 16; ++p) acc[p] = 0.f;
    if (o < 18) {
      for (int ci = g * 16; ci < g * 16 + 16; ++ci) {
        float xr[16];
#pragma unroll
        for (int p = 0; p < 16; ++p) xr[p] = xn[ci * 16 + p];
        const float* wrow = Wpt + (ci * 9) * 18 + o;
#pragma unroll
        for (int kx = 0; kx < 3; ++kx) {
#pragma unroll
          for (int ky = 0; ky < 3; ++ky) {
            float wv = wrow[(kx * 3 + ky) * 18];
#pragma unroll
            for (int h = 0; h < 4; ++h) {
              int ih = h + kx - 1;
              if (ih < 0 || ih > 3) continue;
#pragma unroll
              for (int w = 0; w < 4; ++w) {
                int iw = w + ky - 1;
                if (iw < 0 || iw > 3) continue;
                acc[h * 4 + w] += wv * xr[ih * 4 + iw];
              }
            }
          }
        }
      }
#pragma unroll
      for (int p = 0; p < 16; ++p) xoff[g * 288 + o * 16 + p] = acc[p];  // reuse xoff as scratch
    }
  }
  __syncthreads();
  // reduce offset partials + bias
  for (int i = t; i < 288; i += 256) {
    int o = i >> 4;
    float v = bp[o];
#pragma unroll
    for (int g = 0; g < 8; ++g) v += xoff[g * 288 + i];
    offs[i] = v;
  }
  __syncthreads();
  // C: sampling metadata per (px, n)
  if (t < 144) {
    int p = t / 9, n = t % 9;
    int h = p >> 2, w = p & 3;
    float sx = offs[n * 16 + p] + (float)(h + 1) + (float)(n / 3 - 1);
    float sy = offs[(9 + n) * 16 + p] + (float)(w + 1) + (float)(n % 3 - 1);
    float fx = floorf(sx), fy = floorf(sy);
    float qlx = fminf(fmaxf(fx, 0.f), 5.f);
    float qly = fminf(fmaxf(fy, 0.f), 5.f);
    float qrx = fminf(fmaxf(fx + 1.f, 0.f), 5.f);
    float qry = fminf(fmaxf(fy + 1.f, 0.f), 5.f);
    float pxc = fminf(fmaxf(sx, 0.f), 5.f);
    float pyc = fminf(fmaxf(sy, 0.f), 5.f);
    float glt = (1.f + (qlx - pxc)) * (1.f + (qly - pyc));
    float grb = (1.f - (qrx - pxc)) * (1.f - (qry - pyc));
    float glb = (1.f + (qlx - pxc)) * (1.f - (qry - pyc));
    float grt = (1.f - (qrx - pxc)) * (1.f + (qly - pyc));
    int ilx = (int)qlx, ily = (int)qly, irx = (int)qrx, iry = (int)qry;
    int base = (p * 9 + n) * 4;
    auto MAP = [](int qx, int qy) {
      return (qx >= 1 && qx <= 4 && qy >= 1 && qy <= 4) ? ((qx - 1) * 4 + (qy - 1)) : -1;
    };
    qidx[base + 0] = MAP(ilx, ily); qwgt[base + 0] = glt;
    qidx[base + 1] = MAP(irx, iry); qwgt[base + 1] = grb;
    qidx[base + 2] = MAP(ilx, iry); qwgt[base + 2] = glb;
    qidx[base + 3] = MAP(irx, ily); qwgt[base + 3] = grt;
  }
  __syncthreads();
  // D: matvec out[co][px] = sum_{ci,n} Wd[co][ci][n] * xoff[ci][n][px]
  int wv = t >> 6, lane = t & 63;
  int p = lane & 15, cg = lane >> 4;
  int cobase = wv * 32 + cg * 8;
  float acc[8];
#pragma unroll
  for (int j = 0; j < 8; ++j) acc[j] = 0.f;
  for (int chunk = 0; chunk < 2; ++chunk) {
    // D1: build xoff for cin chunk
    for (int i = t; i < 9216; i += 256) {
      int cl = i / 144, r = i % 144;  // r = n*16+p
      int ci = chunk * 64 + cl;
      int pp = r & 15, n = r >> 4;
      int base = (pp * 9 + n) * 4;
      float v = 0.f;
#pragma unroll
      for (int j = 0; j < 4; ++j) {
        int ix = qidx[base + j];
        float xv = (ix >= 0) ? xn[ci * 16 + ix] : 0.f;
        v += qwgt[base + j] * xv;
      }
      xoff[i] = v;  // layout [cl][n][px] == linear i
    }
    __syncthreads();
    // D2: accumulate
    for (int cl = 0; cl < 64; ++cl) {
      int ci = chunk * 64 + cl;
      const float* wdrow = Wdt + (ci * 9) * 128 + cobase;
#pragma unroll
      for (int n = 0; n < 9; ++n) {
        float xv = xoff[(cl * 9 + n) * 16 + p];
        const float4* w4 = (const float4*)(wdrow + n * 128);
        float4 wa = w4[0], wb = w4[1];
        acc[0] += wa.x * xv; acc[1] += wa.y * xv; acc[2] += wa.z * xv; acc[3] += wa.w * xv;
        acc[4] += wb.x * xv; acc[5] += wb.y * xv; acc[6] += wb.z * xv; acc[7] += wb.w * xv;
      }
    }
    __syncthreads();
  }
  // write + stats
#pragma unroll
  for (int j = 0; j < 8; ++j) {
    float v = fmaxf(acc[j], 0.f);
    y4[b * 2048 + (cobase + j) * 16 + p] = v;
    atomicAdd(&sst[cobase + j], v);
    atomicAdd(&sst[128 + cobase + j], v * v);
  }
  __syncthreads();
  atomicAdd(&st[t], sst[t]);
}

// final: BN4 fold + spatial mean + linear
__global__ __launch_bounds__(128) void k_final(const float* __restrict__ y4, const float* __restrict__ sc4,
                                               const float* __restrict__ Wc, const float* __restrict__ bc,
                                               float* __restrict__ out) {
  __shared__ float vs[128];
  int b = blockIdx.x, t = threadIdx.x;  // t = channel
  const float4* yp = (const float4*)(y4 + b * 2048 + t * 16);
  float4 a0 = yp[0], a1 = yp[1], a2 = yp[2], a3 = yp[3];
  float s = a0.x + a0.y + a0.z + a0.w + a1.x + a1.y + a1.z + a1.w +
            a2.x + a2.y + a2.z + a2.w + a3.x + a3.y + a3.z + a3.w;
  vs[t] = sc4[t] * (s * (1.f / 16.f)) + sc4[128 + t];
  __syncthreads();
  if (t < 10) {
    float acc = bc[t];
    for (int c = 0; c < 128; ++c) acc += Wc[t * 128 + c] * vs[c];
    out[b * 10 + t] = acc;
  }
}

extern "C" void kernel_launch(void* const* d_in, const int* in_sizes, int n_in,
                              void* d_out, int out_size, void* d_ws, size_t ws_size,
                              hipStream_t stream) {
  const float* x  = (const float*)d_in[0];
  const float* W1 = (const float*)d_in[1];
  const float* g1 = (const float*)d_in[2];
  const float* b1 = (const float*)d_in[3];
  const float* W2 = (const float*)d_in[4];
  const float* g2 = (const float*)d_in[5];
  const float* b2 = (const float*)d_in[6];
  const float* W3 = (const float*)d_in[7];
  const float* g3 = (const float*)d_in[8];
  const float* b3 = (const float*)d_in[9];
  const float* Wp = (const float*)d_in[10];
  const float* bp = (const float*)d_in[11];
  const float* Wd = (const float*)d_in[12];
  const float* g4 = (const float*)d_in[13];
  const float* b4 = (const float*)d_in[14];
  const float* Wc = (const float*)d_in[15];
  const float* bc = (const float*)d_in[16];
  float* ws = (float*)d_ws;
  float* out = (float*)d_out;

  hipMemsetAsync(ws + OFF_ST, 0, 1024 * sizeof(float), stream);
  k_transpose<<<(64 * 32 * 9 + 255) / 256, 256, 0, stream>>>(W2, ws + OFF_W2T, 64, 32);
  k_transpose<<<(128 * 64 * 9 + 255) / 256, 256, 0, stream>>>(W3, ws + OFF_W3T, 128, 64);
  k_transpose<<<(18 * 128 * 9 + 255) / 256, 256, 0, stream>>>(Wp, ws + OFF_WPT, 18, 128);
  k_transpose<<<(128 * 128 * 9 + 255) / 256, 256, 0, stream>>>(Wd, ws + OFF_WDT, 128, 128);

  k_conv1<<<NB, 256, 0, stream>>>(x, W1, ws + OFF_Y1, ws + OFF_ST);
  k_finalize<<<1, 128, 0, stream>>>(ws + OFF_ST, g1, b1, ws + OFF_SC, 32);
  k_conv<64, 32, 4><<<NB, 256, 0, stream>>>(ws + OFF_Y1, ws + OFF_W2T, ws + OFF_SC, ws + OFF_Y2, ws + OFF_ST + 256);
  k_finalize<<<1, 128, 0, stream>>>(ws + OFF_ST + 256, g2, b2, ws + OFF_SC + 256, 64);
  k_conv<128, 64, 2><<<NB, 256, 0, stream>>>(ws + OFF_Y2, ws + OFF_W3T, ws + OFF_SC + 256, ws + OFF_Y3, ws + OFF_ST + 512);
  k_finalize<<<1, 128, 0, stream>>>(ws + OFF_ST + 512, g3, b3, ws + OFF_SC + 512, 128);
  k_deform<<<NB, 256, 0, stream>>>(ws + OFF_Y3, ws + OFF_WPT, bp, ws + OFF_WDT, ws + OFF_SC + 512, ws + OFF_Y4, ws + OFF_ST + 768);
  k_finalize<<<1, 128, 0, stream>>>(ws + OFF_ST + 768, g4, b4, ws + OFF_SC + 768, 128);
  k_final<<<NB, 128, 0, stream>>>(ws + OFF_Y4, ws + OFF_SC + 768, Wc, bc, out);
}

// Round 2
// 417.818 us; speedup vs baseline: 2.1314x; 2.1314x over previous
//
#include <hip/hip_runtime.h>

#define NB 2048
#define CNT 32768.0f   // per-channel count = B*H*W = 2048*16

// workspace float offsets
#define OFF_Y1   0          // 2048*32*16
#define OFF_Y2   1048576    // 2048*64*16
#define OFF_Y3   3145728    // 2048*128*16
#define OFF_Y4   7340032    // 2048*128*16
#define OFF_ST   11534336   // 4 layers x 256 (sum[c] at +c, sumsq at +128+c)
#define OFF_SC   11535360   // 4 layers x 256 (s at +c, t at +128+c)
#define OFF_W2T  11536384   // 32*9*64
#define OFF_W3T  11554816   // 64*9*128
#define OFF_WPT  11628544   // 128*9*18
#define OFF_WDP  11649280   // packed bf16 Wd: 147456 ushort = 73728 float slots

typedef __attribute__((ext_vector_type(8))) short bf16x8;
typedef __attribute__((ext_vector_type(4))) float f32x4;

__device__ __forceinline__ unsigned short f2bf(float f) {
  union { float f; unsigned int u; } v; v.f = f;
  unsigned int r = v.u + 0x7FFFu + ((v.u >> 16) & 1u);
  return (unsigned short)(r >> 16);
}

__global__ void k_transpose(const float* __restrict__ w, float* __restrict__ wt, int CO, int CI) {
  int i = blockIdx.x * 256 + threadIdx.x;
  int tot = CO * CI * 9;
  if (i >= tot) return;
  int co = i / (CI * 9), r = i % (CI * 9), ci = r / 9, k = r % 9;
  wt[(ci * 9 + k) * CO + co] = w[i];
}

// pack Wd (co, ci, kx, ky) -> bf16 B-fragment layout for 16x16x32 mfma
// k = ci*9 + tap in [0,1152); t = k/32, g = (k%32)/8, j = k%8
// col co: nt = co/16, cc = co%16; lane = g*16+cc
// wdp[((t*8+nt)*64 + lane)*8 + j]
__global__ void k_packwd(const float* __restrict__ Wd, unsigned short* __restrict__ wdp) {
  int i = blockIdx.x * 256 + threadIdx.x;
  if (i >= 128 * 1152) return;
  int co = i / 1152, k = i % 1152;
  int t = k >> 5, kk = k & 31, g = kk >> 3, j = kk & 7;
  int nt = co >> 4, cc = co & 15, l = g * 16 + cc;
  wdp[((t * 8 + nt) * 64 + l) * 8 + j] = f2bf(Wd[i]);
}

__global__ void k_finalize(const float* __restrict__ st, const float* __restrict__ g,
                           const float* __restrict__ b, float* __restrict__ sc, int C) {
  int c = threadIdx.x;
  if (c >= C) return;
  float m = st[c] / CNT;
  float v = st[128 + c] / CNT - m * m;
  float s = g[c] * rsqrtf(fmaxf(v, 0.f) + 1e-5f);
  sc[c] = s;
  sc[128 + c] = b[c] - m * s;
}

// conv1: 3->32, input raw x
__global__ __launch_bounds__(256) void k_conv1(const float* __restrict__ x, const float* __restrict__ W1,
                                               float* __restrict__ y1, float* __restrict__ st) {
  __shared__ float xs[48];
  __shared__ float w1s[864];
  __shared__ float sst[64];
  int b = blockIdx.x, t = threadIdx.x;
  if (t < 48) xs[t] = x[b * 48 + t];
  for (int i = t; i < 864; i += 256) w1s[i] = W1[i];
  if (t < 64) sst[t] = 0.f;
  __syncthreads();
  for (int r = 0; r < 2; ++r) {
    int o = t + r * 256;            // 0..511
    int co = o >> 4, p = o & 15, h = p >> 2, w = p & 3;
    float acc = 0.f;
    for (int ci = 0; ci < 3; ++ci) {
#pragma unroll
      for (int kx = 0; kx < 3; ++kx) {
        int ih = h + kx - 1;
        if (ih < 0 || ih > 3) continue;
#pragma unroll
        for (int ky = 0; ky < 3; ++ky) {
          int iw = w + ky - 1;
          if (iw < 0 || iw > 3) continue;
          acc += w1s[co * 27 + ci * 9 + kx * 3 + ky] * xs[ci * 16 + ih * 4 + iw];
        }
      }
    }
    acc = fmaxf(acc, 0.f);
    y1[b * 512 + o] = acc;
    atomicAdd(&sst[co], acc);
    atomicAdd(&sst[32 + co], acc * acc);
  }
  __syncthreads();
  if (t < 64) atomicAdd(&st[(t < 32) ? t : (96 + t)], sst[t]);
}

// generic conv 3x3 pad1 over 4x4
template <int CO, int CI, int NG>
__global__ __launch_bounds__(256) void k_conv(const float* __restrict__ yin, const float* __restrict__ wt,
                                              const float* __restrict__ sc, float* __restrict__ yout,
                                              float* __restrict__ st) {
  __shared__ float xs[CI * 16];
  __shared__ float pacc[NG][CO * 16];
  __shared__ float sst[2 * CO];
  int b = blockIdx.x, t = threadIdx.x;
  for (int i = t; i < CI * 16; i += 256) {
    int c = i >> 4;
    xs[i] = yin[b * CI * 16 + i] * sc[c] + sc[128 + c];  // fold producer BN
  }
  for (int i = t; i < 2 * CO; i += 256) sst[i] = 0.f;
  __syncthreads();
  int co = t & (CO - 1), g = t / CO;
  constexpr int CPG = CI / NG;
  float acc[16];
#pragma unroll
  for (int p = 0; p < 16; ++p) acc[p] = 0.f;
  for (int ci = g * CPG; ci < (g + 1) * CPG; ++ci) {
    float xr[16];
#pragma unroll
    for (int p = 0; p < 16; ++p) xr[p] = xs[ci * 16 + p];
    const float* wrow = wt + (ci * 9) * CO + co;
#pragma unroll
    for (int kx = 0; kx < 3; ++kx) {
#pragma unroll
      for (int ky = 0; ky < 3; ++ky) {
        float wv = wrow[(kx * 3 + ky) * CO];
#pragma unroll
        for (int h = 0; h < 4; ++h) {
          int ih = h + kx - 1;
          if (ih < 0 || ih > 3) continue;
#pragma unroll
          for (int w = 0; w < 4; ++w) {
            int iw = w + ky - 1;
            if (iw < 0 || iw > 3) continue;
            acc[h * 4 + w] += wv * xr[ih * 4 + iw];
          }
        }
      }
    }
  }
#pragma unroll
  for (int p = 0; p < 16; ++p) pacc[g][co * 16 + p] = acc[p];
  __syncthreads();
  for (int i = t; i < CO * 16; i += 256) {
    float v = 0.f;
#pragma unroll
    for (int g2 = 0; g2 < NG; ++g2) v += pacc[g2][i];
    v = fmaxf(v, 0.f);
    yout[b * CO * 16 + i] = v;
    int c = i >> 4;
    atomicAdd(&sst[c], v);
    atomicAdd(&sst[CO + c], v * v);
  }
  __syncthreads();
  for (int i = t; i < 2 * CO; i += 256)
    atomicAdd(&st[(i < CO) ? i : (128 - CO + i)], sst[i]);
}

// deformable conv: fp32 offset conv + fp32 bilinear sampling into bf16 MFMA A-fragments,
// then 16x128x1152 GEMM on matrix cores. relu + stats.
__global__ __launch_bounds__(256) void k_deform(const float* __restrict__ y3, const float* __restrict__ Wpt,
                                                const float* __restrict__ bp, const unsigned short* __restrict__ wdp,
                                                const float* __restrict__ sc3, float* __restrict__ y4,
                                                float* __restrict__ st) {
  __shared__ float xn[2048];                         // normalized input image [ci][px]
  __shared__ __align__(16) unsigned short xoffA[18432];  // A fragments: [t(36)][lane(64)][j(8)] bf16
  __shared__ float offs[288];                        // offset conv output [ch(18)][px]
  __shared__ int qidx[576];                          // [px][n][4] interior index or -1
  __shared__ float qwgt[576];
  __shared__ float sst[256];
  float* offscr = (float*)xoffA;                     // 8*288 fp32 partials overlay (dead before A build)

  int b = blockIdx.x, t = threadIdx.x;
  // A: load + normalize
  for (int i = t; i < 2048; i += 256) {
    int c = i >> 4;
    xn[i] = y3[b * 2048 + i] * sc3[c] + sc3[128 + c];
  }
  sst[t] = 0.f;
  __syncthreads();
  // B: offset conv partials (fp32): o = t&31 (active o<18), g = t>>5 covers 16 cin each
  {
    int o = t & 31, g = t >> 5;
    if (o < 18) {
      float acc[16];
#pragma unroll
      for (int p = 0; p < 16; ++p) acc[p] = 0.f;
      for (int ci = g * 16; ci < g * 16 + 16; ++ci) {
        float xr[16];
#pragma unroll
        for (int p = 0; p < 16; ++p) xr[p] = xn[ci * 16 + p];
        const float* wrow = Wpt + (ci * 9) * 18 + o;
#pragma unroll
        for (int kx = 0; kx < 3; ++kx) {
#pragma unroll
          for (int ky = 0; ky < 3; ++ky) {
            float wv = wrow[(kx * 3 + ky) * 18];
#pragma unroll
            for (int h = 0; h < 4; ++h) {
              int ih = h + kx - 1;
              if (ih < 0 || ih > 3) continue;
#pragma unroll
              for (int w = 0; w < 4; ++w) {
                int iw = w + ky - 1;
                if (iw < 0 || iw > 3) continue;
                acc[h * 4 + w] += wv * xr[ih * 4 + iw];
              }
            }
          }
        }
      }
#pragma unroll
      for (int p = 0; p < 16; ++p) offscr[g * 288 + o * 16 + p] = acc[p];
    }
  }
  __syncthreads();
  // reduce offset partials + bias -> offs
  for (int i = t; i < 288; i += 256) {
    int o = i >> 4;
    float v = bp[o];
#pragma unroll
    for (int g = 0; g < 8; ++g) v += offscr[g * 288 + i];
    offs[i] = v;
  }
  __syncthreads();
  // C: sampling metadata per (px, n)
  if (t < 144) {
    int p = t / 9, n = t % 9;
    int h = p >> 2, w = p & 3;
    float sx = offs[n * 16 + p] + (float)(h + 1) + (float)(n / 3 - 1);
    float sy = offs[(9 + n) * 16 + p] + (float)(w + 1) + (float)(n % 3 - 1);
    float fx = floorf(sx), fy = floorf(sy);
    float qlx = fminf(fmaxf(fx, 0.f), 5.f);
    float qly = fminf(fmaxf(fy, 0.f), 5.f);
    float qrx = fminf(fmaxf(fx + 1.f, 0.f), 5.f);
    float qry = fminf(fmaxf(fy + 1.f, 0.f), 5.f);
    float pxc = fminf(fmaxf(sx, 0.f), 5.f);
    float pyc = fminf(fmaxf(sy, 0.f), 5.f);
    float glt = (1.f + (qlx - pxc)) * (1.f + (qly - pyc));
    float grb = (1.f - (qrx - pxc)) * (1.f - (qry - pyc));
    float glb = (1.f + (qlx - pxc)) * (1.f - (qry - pyc));
    float grt = (1.f - (qrx - pxc)) * (1.f + (qly - pyc));
    int ilx = (int)qlx, ily = (int)qly, irx = (int)qrx, iry = (int)qry;
    int base = (p * 9 + n) * 4;
    auto MAP = [](int qx, int qy) {
      return (qx >= 1 && qx <= 4 && qy >= 1 && qy <= 4) ? ((qx - 1) * 4 + (qy - 1)) : -1;
    };
    qidx[base + 0] = MAP(ilx, ily); qwgt[base + 0] = glt;
    qidx[base + 1] = MAP(irx, iry); qwgt[base + 1] = grb;
    qidx[base + 2] = MAP(ilx, iry); qwgt[base + 2] = glb;
    qidx[base + 3] = MAP(irx, ily); qwgt[base + 3] = grt;
  }
  __syncthreads();
  // D: build A fragments in bf16. slot s = (t(36), lane(64)); lane: px = l&15, g = l>>4;
  // element j: k = t*32 + g*8 + j; value = xoff[ci = k/9][n = k%9][px]
  for (int s = t; s < 2304; s += 256) {
    int tt = s >> 6, l = s & 63;
    int px = l & 15, g = l >> 4;
    int kbase = tt * 32 + g * 8;
    union { unsigned short u16[8]; uint4 u4; } tmp;
#pragma unroll
    for (int j = 0; j < 8; ++j) {
      int k = kbase + j;
      int ci = k / 9;
      int n = k - ci * 9;
      int base = (px * 9 + n) * 4;
      float v = 0.f;
#pragma unroll
      for (int q = 0; q < 4; ++q) {
        int ix = qidx[base + q];
        v += (ix >= 0) ? qwgt[base + q] * xn[ci * 16 + ix] : 0.f;
      }
      tmp.u16[j] = f2bf(v);
    }
    *(uint4*)&xoffA[s * 8] = tmp.u4;
  }
  __syncthreads();
  // E: MFMA GEMM: wave wv handles N-tiles 2wv, 2wv+1. 36 K-steps.
  int wv = t >> 6, l = t & 63;
  f32x4 acc0 = {0.f, 0.f, 0.f, 0.f};
  f32x4 acc1 = {0.f, 0.f, 0.f, 0.f};
  for (int tt = 0; tt < 36; ++tt) {
    bf16x8 a  = *(const bf16x8*)&xoffA[(tt * 64 + l) * 8];
    bf16x8 b0 = *(const bf16x8*)&wdp[(((tt * 8) + 2 * wv) * 64 + l) * 8];
    bf16x8 b1 = *(const bf16x8*)&wdp[(((tt * 8) + 2 * wv + 1) * 64 + l) * 8];
    acc0 = __builtin_amdgcn_mfma_f32_16x16x32_bf16(a, b0, acc0, 0, 0, 0);
    acc1 = __builtin_amdgcn_mfma_f32_16x16x32_bf16(a, b1, acc1, 0, 0, 0);
  }
  // F: write + stats. D layout: row(px) = (l>>4)*4 + r, col(cc) = l&15
  {
    int cc = l & 15, rg = l >> 4;
    int co0 = (2 * wv) * 16 + cc, co1 = (2 * wv + 1) * 16 + cc;
    float s1a = 0.f, s2a = 0.f, s1b = 0.f, s2b = 0.f;
#pragma unroll
    for (int r = 0; r < 4; ++r) {
      int px = rg * 4 + r;
      float v0 = fmaxf(acc0[r], 0.f);
      float v1 = fmaxf(acc1[r], 0.f);
      y4[b * 2048 + co0 * 16 + px] = v0;
      y4[b * 2048 + co1 * 16 + px] = v1;
      s1a += v0; s2a += v0 * v0;
      s1b += v1; s2b += v1 * v1;
    }
    atomicAdd(&sst[co0], s1a); atomicAdd(&sst[128 + co0], s2a);
    atomicAdd(&sst[co1], s1b); atomicAdd(&sst[128 + co1], s2b);
  }
  __syncthreads();
  atomicAdd(&st[t], sst[t]);
}

// final: BN4 fold + spatial mean + linear
__global__ __launch_bounds__(128) void k_final(const float* __restrict__ y4, const float* __restrict__ sc4,
                                               const float* __restrict__ Wc, const float* __restrict__ bc,
                                               float* __restrict__ out) {
  __shared__ float vs[128];
  int b = blockIdx.x, t = threadIdx.x;  // t = channel
  const float4* yp = (const float4*)(y4 + b * 2048 + t * 16);
  float4 a0 = yp[0], a1 = yp[1], a2 = yp[2], a3 = yp[3];
  float s = a0.x + a0.y + a0.z + a0.w + a1.x + a1.y + a1.z + a1.w +
            a2.x + a2.y + a2.z + a2.w + a3.x + a3.y + a3.z + a3.w;
  vs[t] = sc4[t] * (s * (1.f / 16.f)) + sc4[128 + t];
  __syncthreads();
  if (t < 10) {
    float acc = bc[t];
    for (int c = 0; c < 128; ++c) acc += Wc[t * 128 + c] * vs[c];
    out[b * 10 + t] = acc;
  }
}

extern "C" void kernel_launch(void* const* d_in, const int* in_sizes, int n_in,
                              void* d_out, int out_size, void* d_ws, size_t ws_size,
                              hipStream_t stream) {
  const float* x  = (const float*)d_in[0];
  const float* W1 = (const float*)d_in[1];
  const float* g1 = (const float*)d_in[2];
  const float* b1 = (const float*)d_in[3];
  const float* W2 = (const float*)d_in[4];
  const float* g2 = (const float*)d_in[5];
  const float* b2 = (const float*)d_in[6];
  const float* W3 = (const float*)d_in[7];
  const float* g3 = (const float*)d_in[8];
  const float* b3 = (const float*)d_in[9];
  const float* Wp = (const float*)d_in[10];
  const float* bp = (const float*)d_in[11];
  const float* Wd = (const float*)d_in[12];
  const float* g4 = (const float*)d_in[13];
  const float* b4 = (const float*)d_in[14];
  const float* Wc = (const float*)d_in[15];
  const float* bc = (const float*)d_in[16];
  float* ws = (float*)d_ws;
  float* out = (float*)d_out;

  hipMemsetAsync(ws + OFF_ST, 0, 1024 * sizeof(float), stream);
  k_transpose<<<(64 * 32 * 9 + 255) / 256, 256, 0, stream>>>(W2, ws + OFF_W2T, 64, 32);
  k_transpose<<<(128 * 64 * 9 + 255) / 256, 256, 0, stream>>>(W3, ws + OFF_W3T, 128, 64);
  k_transpose<<<(18 * 128 * 9 + 255) / 256, 256, 0, stream>>>(Wp, ws + OFF_WPT, 18, 128);
  k_packwd<<<(128 * 1152 + 255) / 256, 256, 0, stream>>>(Wd, (unsigned short*)(ws + OFF_WDP));

  k_conv1<<<NB, 256, 0, stream>>>(x, W1, ws + OFF_Y1, ws + OFF_ST);
  k_finalize<<<1, 128, 0, stream>>>(ws + OFF_ST, g1, b1, ws + OFF_SC, 32);
  k_conv<64, 32, 4><<<NB, 256, 0, stream>>>(ws + OFF_Y1, ws + OFF_W2T, ws + OFF_SC, ws + OFF_Y2, ws + OFF_ST + 256);
  k_finalize<<<1, 128, 0, stream>>>(ws + OFF_ST + 256, g2, b2, ws + OFF_SC + 256, 64);
  k_conv<128, 64, 2><<<NB, 256, 0, stream>>>(ws + OFF_Y2, ws + OFF_W3T, ws + OFF_SC + 256, ws + OFF_Y3, ws + OFF_ST + 512);
  k_finalize<<<1, 128, 0, stream>>>(ws + OFF_ST + 512, g3, b3, ws + OFF_SC + 512, 128);
  k_deform<<<NB, 256, 0, stream>>>(ws + OFF_Y3, ws + OFF_WPT, bp, (const unsigned short*)(ws + OFF_WDP),
                                   ws + OFF_SC + 512, ws + OFF_Y4, ws + OFF_ST + 768);
  k_finalize<<<1, 128, 0, stream>>>(ws + OFF_ST + 768, g4, b4, ws + OFF_SC + 768, 128);
  k_final<<<NB, 128, 0, stream>>>(ws + OFF_Y4, ws + OFF_SC + 768, Wc, bc, out);
}

// Round 3
// 312.687 us; speedup vs baseline: 2.8480x; 1.3362x over previous
//
#include <hip/hip_runtime.h>

#define NB 2048
#define CNT 32768.0f   // per-channel count = B*H*W = 2048*16

// workspace float offsets
#define OFF_Y1   0          // 2048*32*16
#define OFF_Y2   1048576    // 2048*64*16
#define OFF_Y3   3145728    // 2048*128*16
#define OFF_Y4   7340032    // 2048*128*16
#define OFF_ST   11534336   // 4 layers x 256
#define OFF_SC   11535360   // 4 layers x 256
#define OFF_W2P  11536384   // conv2 pack: 9*4*512 ushort = 9216 float
#define OFF_W3P  11545600   // conv3 pack: 18*8*512 ushort = 36864 float
#define OFF_WPP  11582464   // offset-conv pack: 36*2*512 ushort = 18432 float
#define OFF_WDP  11600896   // Wd pack: 147456 ushort = 73728 float

typedef __attribute__((ext_vector_type(8))) short bf16x8;
typedef __attribute__((ext_vector_type(4))) float f32x4;

__device__ __forceinline__ unsigned short f2bf(float f) {
  union { float f; unsigned int u; } v; v.f = f;
  unsigned int r = v.u + 0x7FFFu + ((v.u >> 16) & 1u);
  return (unsigned short)(r >> 16);
}

// pack conv weight [CO][CI][3][3] -> bf16 B-fragments, tap-major K order.
// dest i = ((step*NT + nt)*64 + l)*8 + j ; step = tap*(CI/32)+ks ;
// k-within-step: ci = ks*32 + (l>>4)*8 + j ; col co = nt*16 + (l&15) (zero-pad co>=CO)
__global__ void k_packw(const float* __restrict__ w, unsigned short* __restrict__ wpk,
                        int CI, int CO, int NT) {
  int KST = CI >> 5;
  int tot = 9 * KST * NT * 512;
  int i = blockIdx.x * 256 + threadIdx.x;
  if (i >= tot) return;
  int j = i & 7, l = (i >> 3) & 63, sn = i >> 9;
  int nt = sn % NT, step = sn / NT;
  int tap = step / KST, ks = step - tap * KST;
  int g = l >> 4, cc = l & 15;
  int ci = ks * 32 + g * 8 + j, co = nt * 16 + cc;
  wpk[i] = (co < CO) ? f2bf(w[(co * CI + ci) * 9 + tap]) : (unsigned short)0;
}

// pack Wd (co, ci, kx, ky) -> bf16 B-fragment layout, K order k = ci*9 + tap (R2-verified)
__global__ void k_packwd(const float* __restrict__ Wd, unsigned short* __restrict__ wdp) {
  int i = blockIdx.x * 256 + threadIdx.x;
  if (i >= 128 * 1152) return;
  int co = i / 1152, k = i % 1152;
  int t = k >> 5, kk = k & 31, g = kk >> 3, j = kk & 7;
  int nt = co >> 4, cc = co & 15, l = g * 16 + cc;
  wdp[((t * 8 + nt) * 64 + l) * 8 + j] = f2bf(Wd[i]);
}

__global__ void k_finalize(const float* __restrict__ st, const float* __restrict__ g,
                           const float* __restrict__ b, float* __restrict__ sc, int C) {
  int c = threadIdx.x;
  if (c >= C) return;
  float m = st[c] / CNT;
  float v = st[128 + c] / CNT - m * m;
  float s = g[c] * rsqrtf(fmaxf(v, 0.f) + 1e-5f);
  sc[c] = s;
  sc[128 + c] = b[c] - m * s;
}

// conv1: 3->32, fp32 (tiny)
__global__ __launch_bounds__(256) void k_conv1(const float* __restrict__ x, const float* __restrict__ W1,
                                               float* __restrict__ y1, float* __restrict__ st) {
  __shared__ float xs[48];
  __shared__ float w1s[864];
  __shared__ float sst[64];
  int b = blockIdx.x, t = threadIdx.x;
  if (t < 48) xs[t] = x[b * 48 + t];
  for (int i = t; i < 864; i += 256) w1s[i] = W1[i];
  if (t < 64) sst[t] = 0.f;
  __syncthreads();
  for (int r = 0; r < 2; ++r) {
    int o = t + r * 256;
    int co = o >> 4, p = o & 15, h = p >> 2, w = p & 3;
    float acc = 0.f;
    for (int ci = 0; ci < 3; ++ci) {
#pragma unroll
      for (int kx = 0; kx < 3; ++kx) {
        int ih = h + kx - 1;
        if (ih < 0 || ih > 3) continue;
#pragma unroll
        for (int ky = 0; ky < 3; ++ky) {
          int iw = w + ky - 1;
          if (iw < 0 || iw > 3) continue;
          acc += w1s[co * 27 + ci * 9 + kx * 3 + ky] * xs[ci * 16 + ih * 4 + iw];
        }
      }
    }
    acc = fmaxf(acc, 0.f);
    y1[b * 512 + o] = acc;
    atomicAdd(&sst[co], acc);
    atomicAdd(&sst[32 + co], acc * acc);
  }
  __syncthreads();
  if (t < 64) atomicAdd(&st[(t < 32) ? t : (96 + t)], sst[t]);
}

// MFMA conv 3x3 pad1 over 4x4: zero-padded 6x6 bf16 tile, A = one ds_read_b128 per K-step.
template <int CI, int CO>
__global__ __launch_bounds__(256) void k_convm(const float* __restrict__ yin,
                                               const unsigned short* __restrict__ wpk,
                                               const float* __restrict__ sc,
                                               float* __restrict__ yout, float* __restrict__ st) {
  constexpr int KST = CI / 32, NSTEP = 9 * KST, NT = CO / 16, TPW = NT / 4;
  constexpr int STR = (CI == 128) ? 136 : 72;  // ushort stride: 16B-aligned rows, 2-way-free banks
  __shared__ __align__(16) unsigned short xnT[36 * STR];
  __shared__ float cst[CO * 16];
  __shared__ float sst[2 * CO];
  int b = blockIdx.x, t = threadIdx.x;
  uint4 z = {0u, 0u, 0u, 0u};
  for (int i = t; i < (36 * STR) / 8; i += 256) ((uint4*)xnT)[i] = z;
  for (int i = t; i < 2 * CO; i += 256) sst[i] = 0.f;
  __syncthreads();
  for (int i = t; i < CI * 16; i += 256) {
    int c = i >> 4, p = i & 15, h = p >> 2, w = p & 3;
    float v = yin[b * CI * 16 + i] * sc[c] + sc[128 + c];
    xnT[((h + 1) * 6 + (w + 1)) * STR + c] = f2bf(v);
  }
  __syncthreads();
  int wv = t >> 6, l = t & 63, px = l & 15, g = l >> 4;
  int h = px >> 2, w = px & 3;
  f32x4 acc[TPW];
#pragma unroll
  for (int tw = 0; tw < TPW; ++tw) acc[tw] = f32x4{0.f, 0.f, 0.f, 0.f};
#pragma unroll
  for (int step = 0; step < NSTEP; ++step) {
    int tap = step / KST, ks = step - tap * KST;
    int kx = tap / 3, ky = tap % 3;
    bf16x8 a = *(const bf16x8*)&xnT[((h + kx) * 6 + (w + ky)) * STR + ks * 32 + g * 8];
#pragma unroll
    for (int tw = 0; tw < TPW; ++tw) {
      int nt = wv * TPW + tw;
      bf16x8 bb = *(const bf16x8*)&wpk[((step * NT + nt) * 64 + l) * 8];
      acc[tw] = __builtin_amdgcn_mfma_f32_16x16x32_bf16(a, bb, acc[tw], 0, 0, 0);
    }
  }
  int cc = l & 15;
#pragma unroll
  for (int tw = 0; tw < TPW; ++tw) {
    int co = (wv * TPW + tw) * 16 + cc;
#pragma unroll
    for (int r = 0; r < 4; ++r) cst[co * 16 + (g * 4 + r)] = acc[tw][r];
  }
  __syncthreads();
  for (int i = t; i < CO * 16; i += 256) {
    float v = fmaxf(cst[i], 0.f);
    yout[b * CO * 16 + i] = v;
    int c = i >> 4;
    atomicAdd(&sst[c], v);
    atomicAdd(&sst[CO + c], v * v);
  }
  __syncthreads();
  for (int i = t; i < 2 * CO; i += 256)
    atomicAdd(&st[(i < CO) ? i : (128 - CO + i)], sst[i]);
}

// deformable conv: MFMA offset-conv (xnT scheme) + fp32 bilinear A-build + MFMA Wd GEMM
__global__ __launch_bounds__(256) void k_deform(const float* __restrict__ y3,
                                                const unsigned short* __restrict__ wppk,
                                                const float* __restrict__ bp,
                                                const unsigned short* __restrict__ wdp,
                                                const float* __restrict__ sc3,
                                                float* __restrict__ y4, float* __restrict__ st) {
  __shared__ __align__(16) unsigned char smem[51840];
  float* xn = (float*)smem;                                  // [0,8192) f32 image (sampling src)
  unsigned short* xnT = (unsigned short*)(smem + 8192);      // [8192,17984) 36x136 bf16 (offset conv)
  unsigned short* xoffA = (unsigned short*)(smem + 8192);    // [8192,45056) A-frags (after xnT dead)
  float* cscr = (float*)(smem + 28672);                      // [28672,30720) offset-conv partials
  float* ystg = (float*)smem;                                // epilogue staging (after xn dead)
  float* offs = (float*)(smem + 45056);                      // 288 f32
  int* qidx = (int*)(smem + 46208);                          // 576
  float* qwgt = (float*)(smem + 48512);                      // 576
  float* sst = (float*)(smem + 50816);                       // 256
  int b = blockIdx.x, t = threadIdx.x;
  uint4 z = {0u, 0u, 0u, 0u};
  for (int i = t; i < 612; i += 256) ((uint4*)xnT)[i] = z;
  sst[t] = 0.f;
  __syncthreads();
  for (int i = t; i < 2048; i += 256) {
    int c = i >> 4, p = i & 15, h = p >> 2, w = p & 3;
    float v = y3[b * 2048 + i] * sc3[c] + sc3[128 + c];
    xn[i] = v;
    xnT[((h + 1) * 6 + (w + 1)) * 136 + c] = f2bf(v);
  }
  __syncthreads();
  int wv = t >> 6, l = t & 63, px = l & 15, g = l >> 4;
  int h = px >> 2, w = px & 3;
  // offset conv via MFMA: 36 K-steps (tap-major, CI=128), NT=2 (18 cols + pad).
  // waves: nt = wv&1, K-half = wv>>1; halves reduced through cscr.
  {
    int nt = wv & 1, half = wv >> 1;
    f32x4 oa = {0.f, 0.f, 0.f, 0.f};
#pragma unroll
    for (int si = 0; si < 18; ++si) {
      int s2 = half * 18 + si;
      int tap = s2 >> 2, ks = s2 & 3;
      int kx = tap / 3, ky = tap % 3;
      bf16x8 a = *(const bf16x8*)&xnT[((h + kx) * 6 + (w + ky)) * 136 + ks * 32 + g * 8];
      bf16x8 bb = *(const bf16x8*)&wppk[((s2 * 2 + nt) * 64 + l) * 8];
      oa = __builtin_amdgcn_mfma_f32_16x16x32_bf16(a, bb, oa, 0, 0, 0);
    }
    if (half == 1) {
#pragma unroll
      for (int r = 0; r < 4; ++r) cscr[nt * 256 + (g * 4 + r) * 16 + px] = oa[r];
    }
    __syncthreads();
    if (half == 0) {
      int o = nt * 16 + px;  // C col = l&15
      if (o < 18) {
        float bo = bp[o];
#pragma unroll
        for (int r = 0; r < 4; ++r) {
          int pp = g * 4 + r;  // C row
          offs[o * 16 + pp] = oa[r] + cscr[nt * 256 + pp * 16 + px] + bo;
        }
      }
    }
  }
  __syncthreads();
  // sampling metadata per (px, n) — branchless (invalid -> wgt 0, idx 0)
  if (t < 144) {
    int p = t / 9, n = t % 9;
    int hh = p >> 2, ww = p & 3;
    float sx = offs[n * 16 + p] + (float)(hh + 1) + (float)(n / 3 - 1);
    float sy = offs[(9 + n) * 16 + p] + (float)(ww + 1) + (float)(n % 3 - 1);
    float fx = floorf(sx), fy = floorf(sy);
    float qlx = fminf(fmaxf(fx, 0.f), 5.f);
    float qly = fminf(fmaxf(fy, 0.f), 5.f);
    float qrx = fminf(fmaxf(fx + 1.f, 0.f), 5.f);
    float qry = fminf(fmaxf(fy + 1.f, 0.f), 5.f);
    float pxc = fminf(fmaxf(sx, 0.f), 5.f);
    float pyc = fminf(fmaxf(sy, 0.f), 5.f);
    float glt = (1.f + (qlx - pxc)) * (1.f + (qly - pyc));
    float grb = (1.f - (qrx - pxc)) * (1.f - (qry - pyc));
    float glb = (1.f + (qlx - pxc)) * (1.f - (qry - pyc));
    float grt = (1.f - (qrx - pxc)) * (1.f + (qly - pyc));
    int ilx = (int)qlx, ily = (int)qly, irx = (int)qrx, iry = (int)qry;
    int base = (p * 9 + n) * 4;
    auto PUT = [&](int s, int qx, int qy, float gv) {
      bool ok = (qx >= 1 && qx <= 4 && qy >= 1 && qy <= 4);
      qidx[base + s] = ok ? ((qx - 1) * 4 + (qy - 1)) : 0;
      qwgt[base + s] = ok ? gv : 0.f;
    };
    PUT(0, ilx, ily, glt);
    PUT(1, irx, iry, grb);
    PUT(2, ilx, iry, glb);
    PUT(3, irx, ily, grt);
  }
  __syncthreads();
  // A-build: bilinear sample into bf16 fragments (k = ci*9 + n)
  for (int s = t; s < 2304; s += 256) {
    int tt = s >> 6, l2 = s & 63;
    int px2 = l2 & 15, g2 = l2 >> 4;
    int kbase = tt * 32 + g2 * 8;
    union { unsigned short u16[8]; uint4 u4; } tmp;
#pragma unroll
    for (int j = 0; j < 8; ++j) {
      int k = kbase + j;
      int ci = k / 9;
      int n = k - ci * 9;
      int base = (px2 * 9 + n) * 4;
      float v = qwgt[base + 0] * xn[ci * 16 + qidx[base + 0]]
              + qwgt[base + 1] * xn[ci * 16 + qidx[base + 1]]
              + qwgt[base + 2] * xn[ci * 16 + qidx[base + 2]]
              + qwgt[base + 3] * xn[ci * 16 + qidx[base + 3]];
      tmp.u16[j] = f2bf(v);
    }
    *(uint4*)&xoffA[s * 8] = tmp.u4;
  }
  __syncthreads();
  // Wd GEMM: wave wv -> N-tiles 2wv, 2wv+1; 36 K-steps
  f32x4 acc0 = {0.f, 0.f, 0.f, 0.f};
  f32x4 acc1 = {0.f, 0.f, 0.f, 0.f};
  for (int tt = 0; tt < 36; ++tt) {
    bf16x8 a = *(const bf16x8*)&xoffA[(tt * 64 + l) * 8];
    bf16x8 b0 = *(const bf16x8*)&wdp[(((tt * 8) + 2 * wv) * 64 + l) * 8];
    bf16x8 b1 = *(const bf16x8*)&wdp[(((tt * 8) + 2 * wv + 1) * 64 + l) * 8];
    acc0 = __builtin_amdgcn_mfma_f32_16x16x32_bf16(a, b0, acc0, 0, 0, 0);
    acc1 = __builtin_amdgcn_mfma_f32_16x16x32_bf16(a, b1, acc1, 0, 0, 0);
  }
  // epilogue: stage C (xn region dead), coalesced write + stats
  {
    int ccd = l & 15, rgd = l >> 4;
    int co0 = 2 * wv * 16 + ccd, co1 = co0 + 16;
#pragma unroll
    for (int r = 0; r < 4; ++r) {
      int pxr = rgd * 4 + r;
      ystg[co0 * 16 + pxr] = acc0[r];
      ystg[co1 * 16 + pxr] = acc1[r];
    }
  }
  __syncthreads();
  for (int i = t; i < 2048; i += 256) {
    float v = fmaxf(ystg[i], 0.f);
    y4[b * 2048 + i] = v;
    int c = i >> 4;
    atomicAdd(&sst[c], v);
    atomicAdd(&sst[128 + c], v * v);
  }
  __syncthreads();
  atomicAdd(&st[t], sst[t]);
}

// final: BN4 fold + spatial mean + linear; 4 images per block, 1 wave each
__global__ __launch_bounds__(256) void k_final(const float* __restrict__ y4, const float* __restrict__ sc4,
                                               const float* __restrict__ Wc, const float* __restrict__ bc,
                                               float* __restrict__ out) {
  __shared__ float vs[4][128];
  int t = threadIdx.x, wv = t >> 6, l = t & 63;
  int img = blockIdx.x * 4 + wv;
  const float4* yp = (const float4*)(y4 + img * 2048);
  float4 a0 = yp[l * 8 + 0], a1 = yp[l * 8 + 1], a2 = yp[l * 8 + 2], a3 = yp[l * 8 + 3];
  float4 b0 = yp[l * 8 + 4], b1 = yp[l * 8 + 5], b2 = yp[l * 8 + 6], b3 = yp[l * 8 + 7];
  float s0 = (a0.x + a0.y + a0.z + a0.w) + (a1.x + a1.y + a1.z + a1.w) +
             (a2.x + a2.y + a2.z + a2.w) + (a3.x + a3.y + a3.z + a3.w);
  float s1 = (b0.x + b0.y + b0.z + b0.w) + (b1.x + b1.y + b1.z + b1.w) +
             (b2.x + b2.y + b2.z + b2.w) + (b3.x + b3.y + b3.z + b3.w);
  int c0 = l * 2, c1 = l * 2 + 1;
  vs[wv][c0] = sc4[c0] * (s0 * 0.0625f) + sc4[128 + c0];
  vs[wv][c1] = sc4[c1] * (s1 * 0.0625f) + sc4[128 + c1];
  __syncthreads();
  if (l < 40) {
    int o = l >> 2, q = l & 3;
    float p = 0.f;
    const float* wr = Wc + o * 128 + q * 32;
    const float* vr = &vs[wv][q * 32];
#pragma unroll
    for (int c = 0; c < 32; ++c) p += wr[c] * vr[c];
    p += __shfl_xor(p, 1);
    p += __shfl_xor(p, 2);
    if (q == 0) out[img * 10 + o] = p + bc[o];
  }
}

extern "C" void kernel_launch(void* const* d_in, const int* in_sizes, int n_in,
                              void* d_out, int out_size, void* d_ws, size_t ws_size,
                              hipStream_t stream) {
  const float* x  = (const float*)d_in[0];
  const float* W1 = (const float*)d_in[1];
  const float* g1 = (const float*)d_in[2];
  const float* b1 = (const float*)d_in[3];
  const float* W2 = (const float*)d_in[4];
  const float* g2 = (const float*)d_in[5];
  const float* b2 = (const float*)d_in[6];
  const float* W3 = (const float*)d_in[7];
  const float* g3 = (const float*)d_in[8];
  const float* b3 = (const float*)d_in[9];
  const float* Wp = (const float*)d_in[10];
  const float* bp = (const float*)d_in[11];
  const float* Wd = (const float*)d_in[12];
  const float* g4 = (const float*)d_in[13];
  const float* b4 = (const float*)d_in[14];
  const float* Wc = (const float*)d_in[15];
  const float* bc = (const float*)d_in[16];
  float* ws = (float*)d_ws;
  float* out = (float*)d_out;

  hipMemsetAsync(ws + OFF_ST, 0, 1024 * sizeof(float), stream);
  k_packw<<<72, 256, 0, stream>>>(W2, (unsigned short*)(ws + OFF_W2P), 32, 64, 4);
  k_packw<<<288, 256, 0, stream>>>(W3, (unsigned short*)(ws + OFF_W3P), 64, 128, 8);
  k_packw<<<144, 256, 0, stream>>>(Wp, (unsigned short*)(ws + OFF_WPP), 128, 18, 2);
  k_packwd<<<576, 256, 0, stream>>>(Wd, (unsigned short*)(ws + OFF_WDP));

  k_conv1<<<NB, 256, 0, stream>>>(x, W1, ws + OFF_Y1, ws + OFF_ST);
  k_finalize<<<1, 128, 0, stream>>>(ws + OFF_ST, g1, b1, ws + OFF_SC, 32);
  k_convm<32, 64><<<NB, 256, 0, stream>>>(ws + OFF_Y1, (const unsigned short*)(ws + OFF_W2P),
                                          ws + OFF_SC, ws + OFF_Y2, ws + OFF_ST + 256);
  k_finalize<<<1, 128, 0, stream>>>(ws + OFF_ST + 256, g2, b2, ws + OFF_SC + 256, 64);
  k_convm<64, 128><<<NB, 256, 0, stream>>>(ws + OFF_Y2, (const unsigned short*)(ws + OFF_W3P),
                                           ws + OFF_SC + 256, ws + OFF_Y3, ws + OFF_ST + 512);
  k_finalize<<<1, 128, 0, stream>>>(ws + OFF_ST + 512, g3, b3, ws + OFF_SC + 512, 128);
  k_deform<<<NB, 256, 0, stream>>>(ws + OFF_Y3, (const unsigned short*)(ws + OFF_WPP), bp,
                                   (const unsigned short*)(ws + OFF_WDP),
                                   ws + OFF_SC + 512, ws + OFF_Y4, ws + OFF_ST + 768);
  k_finalize<<<1, 128, 0, stream>>>(ws + OFF_ST + 768, g4, b4, ws + OFF_SC + 768, 128);
  k_final<<<512, 256, 0, stream>>>(ws + OFF_Y4, ws + OFF_SC + 768, Wc, bc, out);
}

// Round 4
// 251.757 us; speedup vs baseline: 3.5373x; 1.2420x over previous
//
#include <hip/hip_runtime.h>

#define NB 2048
#define CNT 32768.0f   // per-channel count = B*H*W = 2048*16

// workspace float offsets
#define OFF_Y1   0          // 2048*32*16
#define OFF_Y2   1048576    // 2048*64*16
#define OFF_Y3   3145728    // 2048*128*16
#define OFF_Y4   7340032    // 2048*128*16
#define OFF_ST   11534336   // 4 layers x 256
#define OFF_SC   11535360   // (unused now)
#define OFF_W2P  11536384   // conv2 pack: 18432 ushort
#define OFF_W3P  11545600   // conv3 pack: 73728 ushort
#define OFF_WPP  11582464   // offset-conv pack: 36864 ushort
#define OFF_WDP  11600896   // Wd pack: 147456 ushort

typedef __attribute__((ext_vector_type(8))) short bf16x8;
typedef __attribute__((ext_vector_type(4))) float f32x4;

__device__ __forceinline__ unsigned short f2bf(float f) {
  union { float f; unsigned int u; } v; v.f = f;
  unsigned int r = v.u + 0x7FFFu + ((v.u >> 16) & 1u);
  return (unsigned short)(r >> 16);
}
__device__ __forceinline__ float bf2f(unsigned short u) {
  union { unsigned int u; float f; } v; v.u = ((unsigned int)u) << 16;
  return v.f;
}

// pack conv weight [CO][CI][3][3] -> bf16 B-fragments, tap-major K (step = tap*KST+ks)
__device__ __forceinline__ void packw_one(const float* __restrict__ w, unsigned short* __restrict__ wpk,
                                          int CI, int CO, int NT, int i) {
  int KST = CI >> 5;
  int j = i & 7, l = (i >> 3) & 63, sn = i >> 9;
  int nt = sn % NT, step = sn / NT;
  int tap = step / KST, ks = step - tap * KST;
  int ci = ks * 32 + (l >> 4) * 8 + j, co = nt * 16 + (l & 15);
  wpk[i] = (co < CO) ? f2bf(w[(co * CI + ci) * 9 + tap]) : (unsigned short)0;
}

// pack Wd: K order k = ci*9 + tap (R2-verified)
__device__ __forceinline__ void packwd_one(const float* __restrict__ Wd, unsigned short* __restrict__ wdp, int i) {
  int co = i / 1152, k = i % 1152;
  int t = k >> 5, kk = k & 31, g = kk >> 3, j = kk & 7;
  int nt = co >> 4, cc = co & 15, l = g * 16 + cc;
  wdp[((t * 8 + nt) * 64 + l) * 8 + j] = f2bf(Wd[i]);
}

// one kernel: all weight packing + stat-buffer zeroing. grid = 1080 blocks x 256.
__global__ void k_packall(const float* __restrict__ W2, const float* __restrict__ W3,
                          const float* __restrict__ Wp, const float* __restrict__ Wd,
                          unsigned short* __restrict__ w2p, unsigned short* __restrict__ w3p,
                          unsigned short* __restrict__ wpp, unsigned short* __restrict__ wdp,
                          float* __restrict__ st) {
  int i = blockIdx.x * 256 + threadIdx.x;
  if (i < 1024) st[i] = 0.f;
  if (i < 18432) packw_one(W2, w2p, 32, 64, 4, i);
  else if (i < 92160) packw_one(W3, w3p, 64, 128, 8, i - 18432);
  else if (i < 129024) packw_one(Wp, wpp, 128, 18, 2, i - 92160);
  else if (i < 276480) packwd_one(Wd, wdp, i - 129024);
}

// conv1: 3->32, fp32 (tiny), writes y1 + st0
__global__ __launch_bounds__(256) void k_conv1(const float* __restrict__ x, const float* __restrict__ W1,
                                               float* __restrict__ y1, float* __restrict__ st) {
  __shared__ float xs[48];
  __shared__ float w1s[864];
  __shared__ float sst[64];
  int b = blockIdx.x, t = threadIdx.x;
  if (t < 48) xs[t] = x[b * 48 + t];
  for (int i = t; i < 864; i += 256) w1s[i] = W1[i];
  if (t < 64) sst[t] = 0.f;
  __syncthreads();
  for (int r = 0; r < 2; ++r) {
    int o = t + r * 256;
    int co = o >> 4, p = o & 15, h = p >> 2, w = p & 3;
    float acc = 0.f;
    for (int ci = 0; ci < 3; ++ci) {
#pragma unroll
      for (int kx = 0; kx < 3; ++kx) {
        int ih = h + kx - 1;
        if (ih < 0 || ih > 3) continue;
#pragma unroll
        for (int ky = 0; ky < 3; ++ky) {
          int iw = w + ky - 1;
          if (iw < 0 || iw > 3) continue;
          acc += w1s[co * 27 + ci * 9 + kx * 3 + ky] * xs[ci * 16 + ih * 4 + iw];
        }
      }
    }
    acc = fmaxf(acc, 0.f);
    y1[b * 512 + o] = acc;
    atomicAdd(&sst[co], acc);
    atomicAdd(&sst[32 + co], acc * acc);
  }
  __syncthreads();
  if (t < 64) atomicAdd(&st[(t < 32) ? t : (96 + t)], sst[t]);
}

// MFMA conv 3x3 pad1 over 4x4; BN-finalize of producer folded in.
template <int CI, int CO>
__global__ __launch_bounds__(256) void k_convm(const float* __restrict__ yin,
                                               const unsigned short* __restrict__ wpk,
                                               const float* __restrict__ stp,
                                               const float* __restrict__ gp,
                                               const float* __restrict__ bpar,
                                               float* __restrict__ yout, float* __restrict__ stout) {
  constexpr int KST = CI / 32, NSTEP = 9 * KST, NT = CO / 16, TPW = NT / 4;
  constexpr int STR = (CI == 128) ? 136 : 72;
  __shared__ __align__(16) unsigned short xnT[36 * STR];
  __shared__ float cst[CO * 16];
  __shared__ float scS[2 * CI];
  __shared__ float sst[2 * CO];
  int b = blockIdx.x, t = threadIdx.x;
  uint4 z = {0u, 0u, 0u, 0u};
  for (int i = t; i < (36 * STR) / 8; i += 256) ((uint4*)xnT)[i] = z;
  if (t < CI) {
    float m = stp[t] / CNT;
    float v = stp[128 + t] / CNT - m * m;
    float s = gp[t] * rsqrtf(fmaxf(v, 0.f) + 1e-5f);
    scS[t] = s; scS[CI + t] = bpar[t] - m * s;
  }
  for (int i = t; i < 2 * CO; i += 256) sst[i] = 0.f;
  __syncthreads();
  for (int i = t; i < CI * 16; i += 256) {
    int c = i >> 4, p = i & 15, h = p >> 2, w = p & 3;
    float v = yin[b * CI * 16 + i] * scS[c] + scS[CI + c];
    xnT[((h + 1) * 6 + (w + 1)) * STR + c] = f2bf(v);
  }
  __syncthreads();
  int wv = t >> 6, l = t & 63, px = l & 15, g = l >> 4;
  int h = px >> 2, w = px & 3;
  f32x4 acc[TPW];
#pragma unroll
  for (int tw = 0; tw < TPW; ++tw) acc[tw] = f32x4{0.f, 0.f, 0.f, 0.f};
#pragma unroll
  for (int step = 0; step < NSTEP; ++step) {
    int tap = step / KST, ks = step - tap * KST;
    int kx = tap / 3, ky = tap % 3;
    bf16x8 a = *(const bf16x8*)&xnT[((h + kx) * 6 + (w + ky)) * STR + ks * 32 + g * 8];
#pragma unroll
    for (int tw = 0; tw < TPW; ++tw) {
      int nt = wv * TPW + tw;
      bf16x8 bb = *(const bf16x8*)&wpk[((step * NT + nt) * 64 + l) * 8];
      acc[tw] = __builtin_amdgcn_mfma_f32_16x16x32_bf16(a, bb, acc[tw], 0, 0, 0);
    }
  }
  int cc = l & 15;
#pragma unroll
  for (int tw = 0; tw < TPW; ++tw) {
    int co = (wv * TPW + tw) * 16 + cc;
#pragma unroll
    for (int r = 0; r < 4; ++r) cst[co * 16 + (g * 4 + r)] = acc[tw][r];
  }
  __syncthreads();
  // epilogue: thread-owns-channel-slice, local stats, float4 stores
  constexpr int EPT = CO * 16 / 256;   // 4 (CO=64) or 8 (CO=128)
  constexpr int TPC = 16 / EPT;
  int c = t / TPC, e0 = (t % TPC) * EPT;
  float s1 = 0.f, s2 = 0.f;
  float vr[EPT];
#pragma unroll
  for (int e = 0; e < EPT; ++e) {
    float v = fmaxf(cst[c * 16 + e0 + e], 0.f);
    vr[e] = v; s1 += v; s2 += v * v;
  }
#pragma unroll
  for (int e = 0; e < EPT; e += 4)
    *(float4*)&yout[b * CO * 16 + c * 16 + e0 + e] = make_float4(vr[e], vr[e + 1], vr[e + 2], vr[e + 3]);
  atomicAdd(&sst[c], s1);
  atomicAdd(&sst[CO + c], s2);
  __syncthreads();
  for (int i = t; i < 2 * CO; i += 256)
    atomicAdd(&stout[(i < CO) ? i : (128 - CO + i)], sst[i]);
}

// deformable conv, compact-LDS version (~28.5 KB -> 5 blocks/CU)
__global__ __launch_bounds__(256, 5) void k_deform(const float* __restrict__ y3,
                                                   const unsigned short* __restrict__ wppk,
                                                   const float* __restrict__ bp,
                                                   const unsigned short* __restrict__ wdp,
                                                   const float* __restrict__ stp,
                                                   const float* __restrict__ gp,
                                                   const float* __restrict__ bpar,
                                                   float* __restrict__ y4, float* __restrict__ stout) {
  __shared__ __align__(16) unsigned char smem[29184];
  unsigned short* xnb  = (unsigned short*)smem;             // [0,4096) bf16 image [ci][px]
  unsigned short* xnT  = (unsigned short*)(smem + 4096);    // [4096,13888) 36x136 padded tile
  unsigned short* xoffA = (unsigned short*)(smem + 13888);  // [13888,23104) 9-step A frags
  float* cscr = (float*)(smem + 13888);                     // overlay: offset-conv partials (2KB)
  float* offs = (float*)(smem + 23104);                     // 288 f32
  unsigned char* qidx = smem + 24256;                       // 576 u8
  float* qwgt = (float*)(smem + 24832);                     // 576 f32
  float* scS  = (float*)(smem + 27136);                     // 256 f32
  float* sst  = (float*)(smem + 28160);                     // 256 f32
  float* ystg = (float*)smem;                               // overlay [0,8192) epilogue staging
  int b = blockIdx.x, t = threadIdx.x;
  uint4 z = {0u, 0u, 0u, 0u};
  for (int i = t; i < 612; i += 256) ((uint4*)xnT)[i] = z;
  if (t < 128) {
    float m = stp[t] / CNT;
    float v = stp[128 + t] / CNT - m * m;
    float s = gp[t] * rsqrtf(fmaxf(v, 0.f) + 1e-5f);
    scS[t] = s; scS[128 + t] = bpar[t] - m * s;
  }
  sst[t] = 0.f;
  __syncthreads();
  for (int i = t; i < 2048; i += 256) {
    int c = i >> 4, p = i & 15, h = p >> 2, w = p & 3;
    float v = y3[b * 2048 + i] * scS[c] + scS[128 + c];
    unsigned short bv = f2bf(v);
    xnb[i] = bv;
    xnT[((h + 1) * 6 + (w + 1)) * 136 + c] = bv;
  }
  __syncthreads();
  int wv = t >> 6, l = t & 63, px = l & 15, g = l >> 4;
  int h = px >> 2, w = px & 3;
  // offset conv via MFMA: nt = wv&1, K-half = wv>>1; halves reduced through cscr
  {
    int nt = wv & 1, half = wv >> 1;
    f32x4 oa = {0.f, 0.f, 0.f, 0.f};
#pragma unroll
    for (int si = 0; si < 18; ++si) {
      int s2 = half * 18 + si;
      int tap = s2 >> 2, ks = s2 & 3;
      int kx = tap / 3, ky = tap % 3;
      bf16x8 a = *(const bf16x8*)&xnT[((h + kx) * 6 + (w + ky)) * 136 + ks * 32 + g * 8];
      bf16x8 bb = *(const bf16x8*)&wppk[((s2 * 2 + nt) * 64 + l) * 8];
      oa = __builtin_amdgcn_mfma_f32_16x16x32_bf16(a, bb, oa, 0, 0, 0);
    }
    if (half == 1) {
#pragma unroll
      for (int r = 0; r < 4; ++r) cscr[nt * 256 + (g * 4 + r) * 16 + px] = oa[r];
    }
    __syncthreads();
    if (half == 0) {
      int o = nt * 16 + px;
      if (o < 18) {
        float bo = bp[o];
#pragma unroll
        for (int r = 0; r < 4; ++r) {
          int pp = g * 4 + r;
          offs[o * 16 + pp] = oa[r] + cscr[nt * 256 + pp * 16 + px] + bo;
        }
      }
    }
  }
  __syncthreads();
  // sampling metadata per (px, n) — branchless
  if (t < 144) {
    int p = t / 9, n = t % 9;
    int hh = p >> 2, ww = p & 3;
    float sx = offs[n * 16 + p] + (float)(hh + 1) + (float)(n / 3 - 1);
    float sy = offs[(9 + n) * 16 + p] + (float)(ww + 1) + (float)(n % 3 - 1);
    float fx = floorf(sx), fy = floorf(sy);
    float qlx = fminf(fmaxf(fx, 0.f), 5.f);
    float qly = fminf(fmaxf(fy, 0.f), 5.f);
    float qrx = fminf(fmaxf(fx + 1.f, 0.f), 5.f);
    float qry = fminf(fmaxf(fy + 1.f, 0.f), 5.f);
    float pxc = fminf(fmaxf(sx, 0.f), 5.f);
    float pyc = fminf(fmaxf(sy, 0.f), 5.f);
    float glt = (1.f + (qlx - pxc)) * (1.f + (qly - pyc));
    float grb = (1.f - (qrx - pxc)) * (1.f - (qry - pyc));
    float glb = (1.f + (qlx - pxc)) * (1.f - (qry - pyc));
    float grt = (1.f - (qrx - pxc)) * (1.f + (qly - pyc));
    int ilx = (int)qlx, ily = (int)qly, irx = (int)qrx, iry = (int)qry;
    int base = (p * 9 + n) * 4;
    auto PUT = [&](int s, int qx, int qy, float gv) {
      bool ok = (qx >= 1 && qx <= 4 && qy >= 1 && qy <= 4);
      qidx[base + s] = ok ? (unsigned char)((qx - 1) * 4 + (qy - 1)) : (unsigned char)0;
      qwgt[base + s] = ok ? gv : 0.f;
    };
    PUT(0, ilx, ily, glt);
    PUT(1, irx, iry, grb);
    PUT(2, ilx, iry, glb);
    PUT(3, irx, ily, grt);
  }
  __syncthreads();
  // GEMM in 4 K-phases of 9 steps: cooperative A-build -> MFMA
  f32x4 acc0 = {0.f, 0.f, 0.f, 0.f};
  f32x4 acc1 = {0.f, 0.f, 0.f, 0.f};
  for (int p = 0; p < 4; ++p) {
    for (int s = t; s < 576; s += 256) {
      int ttl = s >> 6, l2 = s & 63;
      int px2 = l2 & 15, g2 = l2 >> 4;
      int kb = (p * 9 + ttl) * 32 + g2 * 8;
      union { unsigned short u16[8]; uint4 u4; } tmp;
#pragma unroll
      for (int j = 0; j < 8; ++j) {
        int k = kb + j;
        int ci = k / 9;
        int n = k - ci * 9;
        int base = (px2 * 9 + n) * 4;
        float4 wq = *(const float4*)&qwgt[base];
        unsigned idx4 = *(const unsigned*)&qidx[base];
        int cb = ci * 16;
        float v = wq.x * bf2f(xnb[cb + (idx4 & 0xff)])
                + wq.y * bf2f(xnb[cb + ((idx4 >> 8) & 0xff)])
                + wq.z * bf2f(xnb[cb + ((idx4 >> 16) & 0xff)])
                + wq.w * bf2f(xnb[cb + (idx4 >> 24)]);
        tmp.u16[j] = f2bf(v);
      }
      *(uint4*)&xoffA[s * 8] = tmp.u4;
    }
    __syncthreads();
#pragma unroll 3
    for (int ti = 0; ti < 9; ++ti) {
      int tt = p * 9 + ti;
      bf16x8 a = *(const bf16x8*)&xoffA[(ti * 64 + l) * 8];
      bf16x8 b0 = *(const bf16x8*)&wdp[((tt * 8 + 2 * wv) * 64 + l) * 8];
      bf16x8 b1 = *(const bf16x8*)&wdp[((tt * 8 + 2 * wv + 1) * 64 + l) * 8];
      acc0 = __builtin_amdgcn_mfma_f32_16x16x32_bf16(a, b0, acc0, 0, 0, 0);
      acc1 = __builtin_amdgcn_mfma_f32_16x16x32_bf16(a, b1, acc1, 0, 0, 0);
    }
    __syncthreads();
  }
  // stage C (xnb/xnT dead) then coalesced epilogue
  {
    int ccd = l & 15, rgd = l >> 4;
    int co0 = 2 * wv * 16 + ccd, co1 = co0 + 16;
#pragma unroll
    for (int r = 0; r < 4; ++r) {
      ystg[co0 * 16 + rgd * 4 + r] = acc0[r];
      ystg[co1 * 16 + rgd * 4 + r] = acc1[r];
    }
  }
  __syncthreads();
  {
    int c = t >> 1, e0 = (t & 1) * 8;
    float s1 = 0.f, s2 = 0.f;
    float vr[8];
#pragma unroll
    for (int e = 0; e < 8; ++e) {
      float v = fmaxf(ystg[c * 16 + e0 + e], 0.f);
      vr[e] = v; s1 += v; s2 += v * v;
    }
    *(float4*)&y4[b * 2048 + c * 16 + e0] = make_float4(vr[0], vr[1], vr[2], vr[3]);
    *(float4*)&y4[b * 2048 + c * 16 + e0 + 4] = make_float4(vr[4], vr[5], vr[6], vr[7]);
    atomicAdd(&sst[c], s1);
    atomicAdd(&sst[128 + c], s2);
  }
  __syncthreads();
  atomicAdd(&stout[t], sst[t]);
}

// final: BN4-finalize folded + spatial mean + linear; 4 images per block
__global__ __launch_bounds__(256) void k_final(const float* __restrict__ y4,
                                               const float* __restrict__ stp,
                                               const float* __restrict__ gp,
                                               const float* __restrict__ bpar,
                                               const float* __restrict__ Wc, const float* __restrict__ bc,
                                               float* __restrict__ out) {
  __shared__ float vs[4][128];
  __shared__ float scS[256];
  int t = threadIdx.x, wv = t >> 6, l = t & 63;
  if (t < 128) {
    float m = stp[t] / CNT;
    float v = stp[128 + t] / CNT - m * m;
    float s = gp[t] * rsqrtf(fmaxf(v, 0.f) + 1e-5f);
    scS[t] = s; scS[128 + t] = bpar[t] - m * s;
  }
  __syncthreads();
  int img = blockIdx.x * 4 + wv;
  const float4* yp = (const float4*)(y4 + img * 2048);
  float4 a0 = yp[l * 8 + 0], a1 = yp[l * 8 + 1], a2 = yp[l * 8 + 2], a3 = yp[l * 8 + 3];
  float4 b0 = yp[l * 8 + 4], b1 = yp[l * 8 + 5], b2 = yp[l * 8 + 6], b3 = yp[l * 8 + 7];
  float s0 = (a0.x + a0.y + a0.z + a0.w) + (a1.x + a1.y + a1.z + a1.w) +
             (a2.x + a2.y + a2.z + a2.w) + (a3.x + a3.y + a3.z + a3.w);
  float s1 = (b0.x + b0.y + b0.z + b0.w) + (b1.x + b1.y + b1.z + b1.w) +
             (b2.x + b2.y + b2.z + b2.w) + (b3.x + b3.y + b3.z + b3.w);
  int c0 = l * 2, c1 = l * 2 + 1;
  vs[wv][c0] = scS[c0] * (s0 * 0.0625f) + scS[128 + c0];
  vs[wv][c1] = scS[c1] * (s1 * 0.0625f) + scS[128 + c1];
  __syncthreads();
  if (l < 40) {
    int o = l >> 2, q = l & 3;
    float p = 0.f;
    const float* wr = Wc + o * 128 + q * 32;
    const float* vr = &vs[wv][q * 32];
#pragma unroll
    for (int c = 0; c < 32; ++c) p += wr[c] * vr[c];
    p += __shfl_xor(p, 1);
    p += __shfl_xor(p, 2);
    if (q == 0) out[img * 10 + o] = p + bc[o];
  }
}

extern "C" void kernel_launch(void* const* d_in, const int* in_sizes, int n_in,
                              void* d_out, int out_size, void* d_ws, size_t ws_size,
                              hipStream_t stream) {
  const float* x  = (const float*)d_in[0];
  const float* W1 = (const float*)d_in[1];
  const float* g1 = (const float*)d_in[2];
  const float* b1 = (const float*)d_in[3];
  const float* W2 = (const float*)d_in[4];
  const float* g2 = (const float*)d_in[5];
  const float* b2 = (const float*)d_in[6];
  const float* W3 = (const float*)d_in[7];
  const float* g3 = (const float*)d_in[8];
  const float* b3 = (const float*)d_in[9];
  const float* Wp = (const float*)d_in[10];
  const float* bp = (const float*)d_in[11];
  const float* Wd = (const float*)d_in[12];
  const float* g4 = (const float*)d_in[13];
  const float* b4 = (const float*)d_in[14];
  const float* Wc = (const float*)d_in[15];
  const float* bc = (const float*)d_in[16];
  float* ws = (float*)d_ws;
  float* out = (float*)d_out;

  k_packall<<<1080, 256, 0, stream>>>(W2, W3, Wp, Wd,
                                      (unsigned short*)(ws + OFF_W2P), (unsigned short*)(ws + OFF_W3P),
                                      (unsigned short*)(ws + OFF_WPP), (unsigned short*)(ws + OFF_WDP),
                                      ws + OFF_ST);
  k_conv1<<<NB, 256, 0, stream>>>(x, W1, ws + OFF_Y1, ws + OFF_ST);
  k_convm<32, 64><<<NB, 256, 0, stream>>>(ws + OFF_Y1, (const unsigned short*)(ws + OFF_W2P),
                                          ws + OFF_ST, g1, b1, ws + OFF_Y2, ws + OFF_ST + 256);
  k_convm<64, 128><<<NB, 256, 0, stream>>>(ws + OFF_Y2, (const unsigned short*)(ws + OFF_W3P),
                                           ws + OFF_ST + 256, g2, b2, ws + OFF_Y3, ws + OFF_ST + 512);
  k_deform<<<NB, 256, 0, stream>>>(ws + OFF_Y3, (const unsigned short*)(ws + OFF_WPP), bp,
                                   (const unsigned short*)(ws + OFF_WDP),
                                   ws + OFF_ST + 512, g3, b3, ws + OFF_Y4, ws + OFF_ST + 768);
  k_final<<<512, 256, 0, stream>>>(ws + OFF_Y4, ws + OFF_ST + 768, g4, b4, Wc, bc, out);
}

// Round 5
// 193.151 us; speedup vs baseline: 4.6106x; 1.3034x over previous
//
#include <hip/hip_runtime.h>

#define NB 2048
#define CNT 32768.0f   // per-channel count = B*H*W = 2048*16

// workspace float offsets
#define OFF_Y1   0          // 2048*32*16
#define OFF_Y2   1048576    // 2048*64*16
#define OFF_Y3   3145728    // 2048*128*16
#define OFF_Y4   7340032    // 2048*128*16
#define OFF_ST   11534336   // 4 layers x 256
#define OFF_W2P  11536384   // conv2 pack: 18432 ushort
#define OFF_W3P  11545600   // conv3 pack: 73728 ushort
#define OFF_WPP  11582464   // offset-conv pack: 36864 ushort
#define OFF_WDP  11600896   // Wd pack: 147456 ushort

typedef __attribute__((ext_vector_type(8))) short bf16x8;
typedef __attribute__((ext_vector_type(4))) float f32x4;

__device__ __forceinline__ unsigned short f2bf(float f) {
  union { float f; unsigned int u; } v; v.f = f;
  unsigned int r = v.u + 0x7FFFu + ((v.u >> 16) & 1u);
  return (unsigned short)(r >> 16);
}

// pack conv weight [CO][CI][3][3] -> bf16 B-fragments, tap-major K (step = tap*KST+ks)
__device__ __forceinline__ void packw_one(const float* __restrict__ w, unsigned short* __restrict__ wpk,
                                          int CI, int CO, int NT, int i) {
  int KST = CI >> 5;
  int j = i & 7, l = (i >> 3) & 63, sn = i >> 9;
  int nt = sn % NT, step = sn / NT;
  int tap = step / KST, ks = step - tap * KST;
  int ci = ks * 32 + (l >> 4) * 8 + j, co = nt * 16 + (l & 15);
  wpk[i] = (co < CO) ? f2bf(w[(co * CI + ci) * 9 + tap]) : (unsigned short)0;
}

// pack Wd: K order k = ci*9 + tap (verified)
__device__ __forceinline__ void packwd_one(const float* __restrict__ Wd, unsigned short* __restrict__ wdp, int i) {
  int co = i / 1152, k = i % 1152;
  int t = k >> 5, kk = k & 31, g = kk >> 3, j = kk & 7;
  int nt = co >> 4, cc = co & 15, l = g * 16 + cc;
  wdp[((t * 8 + nt) * 64 + l) * 8 + j] = f2bf(Wd[i]);
}

// merged: blocks [0,1080) pack weights; blocks [1080,3128) run conv1 (3->32, fp32)
__global__ __launch_bounds__(256) void k_pre(const float* __restrict__ W2, const float* __restrict__ W3,
                                             const float* __restrict__ Wp, const float* __restrict__ Wd,
                                             unsigned short* __restrict__ w2p, unsigned short* __restrict__ w3p,
                                             unsigned short* __restrict__ wpp, unsigned short* __restrict__ wdp,
                                             const float* __restrict__ x, const float* __restrict__ W1,
                                             float* __restrict__ y1, float* __restrict__ st) {
  __shared__ float xs[48];
  __shared__ float w1s[864];
  __shared__ float sst[64];
  int t = threadIdx.x;
  if (blockIdx.x < 1080) {
    int i = blockIdx.x * 256 + t;
    if (i < 18432) packw_one(W2, w2p, 32, 64, 4, i);
    else if (i < 92160) packw_one(W3, w3p, 64, 128, 8, i - 18432);
    else if (i < 129024) packw_one(Wp, wpp, 128, 18, 2, i - 92160);
    else if (i < 276480) packwd_one(Wd, wdp, i - 129024);
    return;
  }
  int b = blockIdx.x - 1080;
  if (t < 48) xs[t] = x[b * 48 + t];
  for (int i = t; i < 864; i += 256) w1s[i] = W1[i];
  if (t < 64) sst[t] = 0.f;
  __syncthreads();
  for (int r = 0; r < 2; ++r) {
    int o = t + r * 256;
    int co = o >> 4, p = o & 15, h = p >> 2, w = p & 3;
    float acc = 0.f;
    for (int ci = 0; ci < 3; ++ci) {
#pragma unroll
      for (int kx = 0; kx < 3; ++kx) {
        int ih = h + kx - 1;
        if (ih < 0 || ih > 3) continue;
#pragma unroll
        for (int ky = 0; ky < 3; ++ky) {
          int iw = w + ky - 1;
          if (iw < 0 || iw > 3) continue;
          acc += w1s[co * 27 + ci * 9 + kx * 3 + ky] * xs[ci * 16 + ih * 4 + iw];
        }
      }
    }
    acc = fmaxf(acc, 0.f);
    y1[b * 512 + o] = acc;
    atomicAdd(&sst[co], acc);
    atomicAdd(&sst[32 + co], acc * acc);
  }
  __syncthreads();
  if (t < 64) atomicAdd(&st[(t < 32) ? t : (96 + t)], sst[t]);
}

// MFMA conv 3x3 pad1 over 4x4; 2 images/block (B-fragments shared); producer-BN folded.
template <int CI, int CO>
__global__ __launch_bounds__(256) void k_convm(const float* __restrict__ yin,
                                               const unsigned short* __restrict__ wpk,
                                               const float* __restrict__ stp,
                                               const float* __restrict__ gp,
                                               const float* __restrict__ bpar,
                                               float* __restrict__ yout, float* __restrict__ stout) {
  constexpr int KST = CI / 32, NSTEP = 9 * KST, NT = CO / 16, TPW = NT / 4;
  constexpr int STR = (CI == 128) ? 136 : 72;
  __shared__ __align__(16) unsigned short xnT[2][36 * STR];
  __shared__ float cst[CO * 16];
  __shared__ float scS[2 * CI];
  __shared__ float sst[2 * CO];
  int b0 = blockIdx.x * 2, t = threadIdx.x;
  uint4 z = {0u, 0u, 0u, 0u};
  for (int i = t; i < (2 * 36 * STR) / 8; i += 256) ((uint4*)xnT)[i] = z;
  if (t < CI) {
    float m = stp[t] / CNT;
    float v = stp[128 + t] / CNT - m * m;
    float s = gp[t] * rsqrtf(fmaxf(v, 0.f) + 1e-5f);
    scS[t] = s; scS[CI + t] = bpar[t] - m * s;
  }
  for (int i = t; i < 2 * CO; i += 256) sst[i] = 0.f;
  __syncthreads();
#pragma unroll
  for (int img = 0; img < 2; ++img) {
    for (int i = t; i < CI * 16; i += 256) {
      int c = i >> 4, p = i & 15, h = p >> 2, w = p & 3;
      float v = yin[(b0 + img) * CI * 16 + i] * scS[c] + scS[CI + c];
      xnT[img][((h + 1) * 6 + (w + 1)) * STR + c] = f2bf(v);
    }
  }
  __syncthreads();
  int wv = t >> 6, l = t & 63, px = l & 15, g = l >> 4;
  int h = px >> 2, w = px & 3;
  f32x4 acc[2][TPW];
#pragma unroll
  for (int img = 0; img < 2; ++img)
#pragma unroll
    for (int tw = 0; tw < TPW; ++tw) acc[img][tw] = f32x4{0.f, 0.f, 0.f, 0.f};
#pragma unroll
  for (int step = 0; step < NSTEP; ++step) {
    int tap = step / KST, ks = step - tap * KST;
    int kx = tap / 3, ky = tap % 3;
    bf16x8 bb[TPW];
#pragma unroll
    for (int tw = 0; tw < TPW; ++tw)
      bb[tw] = *(const bf16x8*)&wpk[((step * NT + wv * TPW + tw) * 64 + l) * 8];
    int woff = ((h + kx) * 6 + (w + ky)) * STR + ks * 32 + g * 8;
#pragma unroll
    for (int img = 0; img < 2; ++img) {
      bf16x8 a = *(const bf16x8*)&xnT[img][woff];
#pragma unroll
      for (int tw = 0; tw < TPW; ++tw)
        acc[img][tw] = __builtin_amdgcn_mfma_f32_16x16x32_bf16(a, bb[tw], acc[img][tw], 0, 0, 0);
    }
  }
  int cc = l & 15;
  constexpr int EPT = CO * 16 / 256;
  constexpr int TPC = 16 / EPT;
#pragma unroll
  for (int img = 0; img < 2; ++img) {
#pragma unroll
    for (int tw = 0; tw < TPW; ++tw) {
      int co = (wv * TPW + tw) * 16 + cc;
#pragma unroll
      for (int r = 0; r < 4; ++r) cst[co * 16 + (g * 4 + r)] = acc[img][tw][r];
    }
    __syncthreads();
    int c = t / TPC, e0 = (t % TPC) * EPT;
    float s1 = 0.f, s2 = 0.f;
    float vr[EPT];
#pragma unroll
    for (int e = 0; e < EPT; ++e) {
      float v = fmaxf(cst[c * 16 + e0 + e], 0.f);
      vr[e] = v; s1 += v; s2 += v * v;
    }
#pragma unroll
    for (int e = 0; e < EPT; e += 4)
      *(float4*)&yout[(b0 + img) * CO * 16 + c * 16 + e0 + e] = make_float4(vr[e], vr[e + 1], vr[e + 2], vr[e + 3]);
    atomicAdd(&sst[c], s1);
    atomicAdd(&sst[CO + c], s2);
    __syncthreads();
  }
  for (int i = t; i < 2 * CO; i += 256)
    atomicAdd(&stout[(i < CO) ? i : (128 - CO + i)], sst[i]);
}

// deformable conv: MFMA offset conv + MFMA bilinear (S-matrix) + MFMA Wd GEMM
__global__ __launch_bounds__(256, 5) void k_deform(const float* __restrict__ y3,
                                                   const unsigned short* __restrict__ wppk,
                                                   const float* __restrict__ bp,
                                                   const unsigned short* __restrict__ wdp,
                                                   const float* __restrict__ stp,
                                                   const float* __restrict__ gp,
                                                   const float* __restrict__ bpar,
                                                   float* __restrict__ y4, float* __restrict__ stout) {
  __shared__ __align__(16) unsigned char smem[30400];
  unsigned short* xnb2 = (unsigned short*)smem;             // [0,6144) 128 x 24 ush (bilinear B; [16,24) zero)
  unsigned short* xnT  = (unsigned short*)(smem + 6144);    // [6144,15936) 36x136 padded tile (offset conv)
  unsigned short* sA   = (unsigned short*)(smem + 6144);    // overlay: S frags 9x16x32 (9216B)
  float* cscr = (float*)(smem + 15936);                     // 2KB offset-conv partials
  float* offs = (float*)(smem + 17984);                     // 288 f32
  unsigned short* xoffA = (unsigned short*)(smem + 19136);  // 9*512 ush A-frags (9216B)
  float* scS  = (float*)(smem + 28352);                     // 256 f32
  float* sst  = (float*)(smem + 29376);                     // 256 f32
  float* ystg = (float*)smem;                               // epilogue overlay [0,8192)
  int b = blockIdx.x, t = threadIdx.x;
  uint4 z = {0u, 0u, 0u, 0u};
  for (int i = t; i < 996; i += 256) ((uint4*)smem)[i] = z;  // zero xnb2 + xnT
  if (t < 128) {
    float m = stp[t] / CNT;
    float v = stp[128 + t] / CNT - m * m;
    float s = gp[t] * rsqrtf(fmaxf(v, 0.f) + 1e-5f);
    scS[t] = s; scS[128 + t] = bpar[t] - m * s;
  }
  sst[t] = 0.f;
  __syncthreads();
  for (int i = t; i < 2048; i += 256) {
    int c = i >> 4, p = i & 15, h = p >> 2, w = p & 3;
    float v = y3[b * 2048 + i] * scS[c] + scS[128 + c];
    unsigned short bv = f2bf(v);
    xnb2[c * 24 + p] = bv;
    xnT[((h + 1) * 6 + (w + 1)) * 136 + c] = bv;
  }
  __syncthreads();
  int wv = t >> 6, l = t & 63, px = l & 15, g = l >> 4;
  int h = px >> 2, w = px & 3;
  // offset conv via MFMA: nt = wv&1, K-half = wv>>1; halves reduced through cscr
  {
    int nt = wv & 1, half = wv >> 1;
    f32x4 oa = {0.f, 0.f, 0.f, 0.f};
#pragma unroll
    for (int si = 0; si < 18; ++si) {
      int s2 = half * 18 + si;
      int tap = s2 >> 2, ks = s2 & 3;
      int kx = tap / 3, ky = tap % 3;
      bf16x8 a = *(const bf16x8*)&xnT[((h + kx) * 6 + (w + ky)) * 136 + ks * 32 + g * 8];
      bf16x8 bb = *(const bf16x8*)&wppk[((s2 * 2 + nt) * 64 + l) * 8];
      oa = __builtin_amdgcn_mfma_f32_16x16x32_bf16(a, bb, oa, 0, 0, 0);
    }
    if (half == 1) {
#pragma unroll
      for (int r = 0; r < 4; ++r) cscr[nt * 256 + (g * 4 + r) * 16 + px] = oa[r];
    }
    __syncthreads();
    if (half == 0) {
      int o = nt * 16 + px;
      if (o < 18) {
        float bo = bp[o];
#pragma unroll
        for (int r = 0; r < 4; ++r) {
          int pp = g * 4 + r;
          offs[o * 16 + pp] = oa[r] + cscr[nt * 256 + pp * 16 + px] + bo;
        }
      }
    }
  }
  __syncthreads();
  // zero S fragments (xnT now dead)
  for (int i = t; i < 576; i += 256) ((uint4*)sA)[i] = z;
  __syncthreads();
  // sampling -> scatter bilinear weights into S_n (bf16), chunk-swizzled by (px>>1)&3
  if (t < 144) {
    int p = t / 9, n = t % 9;
    int hh = p >> 2, ww = p & 3;
    float sx = offs[n * 16 + p] + (float)(hh + 1) + (float)(n / 3 - 1);
    float sy = offs[(9 + n) * 16 + p] + (float)(ww + 1) + (float)(n % 3 - 1);
    float fx = floorf(sx), fy = floorf(sy);
    float qlx = fminf(fmaxf(fx, 0.f), 5.f);
    float qly = fminf(fmaxf(fy, 0.f), 5.f);
    float qrx = fminf(fmaxf(fx + 1.f, 0.f), 5.f);
    float qry = fminf(fmaxf(fy + 1.f, 0.f), 5.f);
    float pxc = fminf(fmaxf(sx, 0.f), 5.f);
    float pyc = fminf(fmaxf(sy, 0.f), 5.f);
    float glt = (1.f + (qlx - pxc)) * (1.f + (qly - pyc));
    float grb = (1.f - (qrx - pxc)) * (1.f - (qry - pyc));
    float glb = (1.f + (qlx - pxc)) * (1.f - (qry - pyc));
    float grt = (1.f - (qrx - pxc)) * (1.f + (qly - pyc));
    int ilx = (int)qlx, ily = (int)qly, irx = (int)qrx, iry = (int)qry;
    int sw = (p >> 1) & 3;
    int rowb = (n * 16 + p) * 32;
    auto PUT = [&](int qx, int qy, float gv) {
      if (qx >= 1 && qx <= 4 && qy >= 1 && qy <= 4) {
        int pix = (qx - 1) * 4 + (qy - 1);
        sA[rowb + ((((pix >> 3) + sw) & 3) << 3) + (pix & 7)] = f2bf(gv);
      }
    };
    PUT(ilx, ily, glt);
    PUT(irx, iry, grb);
    PUT(ilx, iry, glb);
    PUT(irx, ily, grt);
  }
  __syncthreads();
  // 4 phases: MFMA bilinear builds xoffA for 9 K-steps, then main GEMM consumes them
  f32x4 acc0 = {0.f, 0.f, 0.f, 0.f};
  f32x4 acc1 = {0.f, 0.f, 0.f, 0.f};
  int sw = (px >> 1) & 3;
  for (int ph = 0; ph < 4; ++ph) {
    for (int tau = wv; tau < 18; tau += 4) {
      int n = tau >> 1, ct = 2 * ph + (tau & 1);
      bf16x8 a = *(const bf16x8*)&sA[(n * 16 + px) * 32 + (((g + sw) & 3) << 3)];
      int ci = ct * 16 + px;
      bf16x8 bv = *(const bf16x8*)&xnb2[ci * 24 + g * 8];
      f32x4 d = __builtin_amdgcn_mfma_f32_16x16x32_bf16(a, bv, f32x4{0.f, 0.f, 0.f, 0.f}, 0, 0, 0);
      int k = ci * 9 + n;
      int tt_l = (k >> 5) - ph * 9, g2 = (k >> 3) & 3, j = k & 7;
      int base = (tt_l * 64 + g2 * 16) * 8 + j;
#pragma unroll
      for (int r = 0; r < 4; ++r) xoffA[base + (g * 4 + r) * 8] = f2bf(d[r]);
    }
    __syncthreads();
#pragma unroll 3
    for (int ti = 0; ti < 9; ++ti) {
      int tt = ph * 9 + ti;
      bf16x8 a = *(const bf16x8*)&xoffA[(ti * 64 + l) * 8];
      bf16x8 b0 = *(const bf16x8*)&wdp[((tt * 8 + 2 * wv) * 64 + l) * 8];
      bf16x8 b1 = *(const bf16x8*)&wdp[((tt * 8 + 2 * wv + 1) * 64 + l) * 8];
      acc0 = __builtin_amdgcn_mfma_f32_16x16x32_bf16(a, b0, acc0, 0, 0, 0);
      acc1 = __builtin_amdgcn_mfma_f32_16x16x32_bf16(a, b1, acc1, 0, 0, 0);
    }
    __syncthreads();
  }
  // stage C then coalesced epilogue (xnb2/sA dead)
  {
    int ccd = l & 15, rgd = l >> 4;
    int co0 = 2 * wv * 16 + ccd, co1 = co0 + 16;
#pragma unroll
    for (int r = 0; r < 4; ++r) {
      ystg[co0 * 16 + rgd * 4 + r] = acc0[r];
      ystg[co1 * 16 + rgd * 4 + r] = acc1[r];
    }
  }
  __syncthreads();
  {
    int c = t >> 1, e0 = (t & 1) * 8;
    float s1 = 0.f, s2 = 0.f;
    float vr[8];
#pragma unroll
    for (int e = 0; e < 8; ++e) {
      float v = fmaxf(ystg[c * 16 + e0 + e], 0.f);
      vr[e] = v; s1 += v; s2 += v * v;
    }
    *(float4*)&y4[b * 2048 + c * 16 + e0] = make_float4(vr[0], vr[1], vr[2], vr[3]);
    *(float4*)&y4[b * 2048 + c * 16 + e0 + 4] = make_float4(vr[4], vr[5], vr[6], vr[7]);
    atomicAdd(&sst[c], s1);
    atomicAdd(&sst[128 + c], s2);
  }
  __syncthreads();
  atomicAdd(&stout[t], sst[t]);
}

// final: BN4-finalize folded + spatial mean + linear; 4 images per block
__global__ __launch_bounds__(256) void k_final(const float* __restrict__ y4,
                                               const float* __restrict__ stp,
                                               const float* __restrict__ gp,
                                               const float* __restrict__ bpar,
                                               const float* __restrict__ Wc, const float* __restrict__ bc,
                                               float* __restrict__ out) {
  __shared__ float vs[4][128];
  __shared__ float scS[256];
  int t = threadIdx.x, wv = t >> 6, l = t & 63;
  if (t < 128) {
    float m = stp[t] / CNT;
    float v = stp[128 + t] / CNT - m * m;
    float s = gp[t] * rsqrtf(fmaxf(v, 0.f) + 1e-5f);
    scS[t] = s; scS[128 + t] = bpar[t] - m * s;
  }
  __syncthreads();
  int img = blockIdx.x * 4 + wv;
  const float4* yp = (const float4*)(y4 + img * 2048);
  float4 a0 = yp[l * 8 + 0], a1 = yp[l * 8 + 1], a2 = yp[l * 8 + 2], a3 = yp[l * 8 + 3];
  float4 b0 = yp[l * 8 + 4], b1 = yp[l * 8 + 5], b2 = yp[l * 8 + 6], b3 = yp[l * 8 + 7];
  float s0 = (a0.x + a0.y + a0.z + a0.w) + (a1.x + a1.y + a1.z + a1.w) +
             (a2.x + a2.y + a2.z + a2.w) + (a3.x + a3.y + a3.z + a3.w);
  float s1 = (b0.x + b0.y + b0.z + b0.w) + (b1.x + b1.y + b1.z + b1.w) +
             (b2.x + b2.y + b2.z + b2.w) + (b3.x + b3.y + b3.z + b3.w);
  int c0 = l * 2, c1 = l * 2 + 1;
  vs[wv][c0] = scS[c0] * (s0 * 0.0625f) + scS[128 + c0];
  vs[wv][c1] = scS[c1] * (s1 * 0.0625f) + scS[128 + c1];
  __syncthreads();
  if (l < 40) {
    int o = l >> 2, q = l & 3;
    float p = 0.f;
    const float* wr = Wc + o * 128 + q * 32;
    const float* vr = &vs[wv][q * 32];
#pragma unroll
    for (int c = 0; c < 32; ++c) p += wr[c] * vr[c];
    p += __shfl_xor(p, 1);
    p += __shfl_xor(p, 2);
    if (q == 0) out[img * 10 + o] = p + bc[o];
  }
}

extern "C" void kernel_launch(void* const* d_in, const int* in_sizes, int n_in,
                              void* d_out, int out_size, void* d_ws, size_t ws_size,
                              hipStream_t stream) {
  const float* x  = (const float*)d_in[0];
  const float* W1 = (const float*)d_in[1];
  const float* g1 = (const float*)d_in[2];
  const float* b1 = (const float*)d_in[3];
  const float* W2 = (const float*)d_in[4];
  const float* g2 = (const float*)d_in[5];
  const float* b2 = (const float*)d_in[6];
  const float* W3 = (const float*)d_in[7];
  const float* g3 = (const float*)d_in[8];
  const float* b3 = (const float*)d_in[9];
  const float* Wp = (const float*)d_in[10];
  const float* bp = (const float*)d_in[11];
  const float* Wd = (const float*)d_in[12];
  const float* g4 = (const float*)d_in[13];
  const float* b4 = (const float*)d_in[14];
  const float* Wc = (const float*)d_in[15];
  const float* bc = (const float*)d_in[16];
  float* ws = (float*)d_ws;
  float* out = (float*)d_out;

  hipMemsetAsync(ws + OFF_ST, 0, 1024 * sizeof(float), stream);
  k_pre<<<3128, 256, 0, stream>>>(W2, W3, Wp, Wd,
                                  (unsigned short*)(ws + OFF_W2P), (unsigned short*)(ws + OFF_W3P),
                                  (unsigned short*)(ws + OFF_WPP), (unsigned short*)(ws + OFF_WDP),
                                  x, W1, ws + OFF_Y1, ws + OFF_ST);
  k_convm<32, 64><<<NB / 2, 256, 0, stream>>>(ws + OFF_Y1, (const unsigned short*)(ws + OFF_W2P),
                                              ws + OFF_ST, g1, b1, ws + OFF_Y2, ws + OFF_ST + 256);
  k_convm<64, 128><<<NB / 2, 256, 0, stream>>>(ws + OFF_Y2, (const unsigned short*)(ws + OFF_W3P),
                                               ws + OFF_ST + 256, g2, b2, ws + OFF_Y3, ws + OFF_ST + 512);
  k_deform<<<NB, 256, 0, stream>>>(ws + OFF_Y3, (const unsigned short*)(ws + OFF_WPP), bp,
                                   (const unsigned short*)(ws + OFF_WDP),
                                   ws + OFF_ST + 512, g3, b3, ws + OFF_Y4, ws + OFF_ST + 768);
  k_final<<<512, 256, 0, stream>>>(ws + OFF_Y4, ws + OFF_ST + 768, g4, b4, Wc, bc, out);
}